// Round 1
// 2331.151 us; speedup vs baseline: 1.0498x; 1.0498x over previous
//
#include <hip/hip_runtime.h>
#include <hip/hip_bf16.h>

// Video_multilevel_encoding — round 6: fuse the 80-step GRU scan (160 launches, ~1650 µs,
// ~67% of runtime) into ONE persistent cooperative kernel.
//   - block (d,bb,cc) owns batch rows bb*32..+32 x h-cols cc*32..+32 (96 Whh rows r/z/n)
//   - Whh slice resident in LDS (97.5 KB, pad-520 rows -> 2-way-free ds_read_b128)
//   - h state in f32 registers (each (row,j) owned by one thread); bf16 h handoff via
//     double-buffered global hbf2[2][2][128][512]
//   - only cross-block dep is within the 16 blocks sharing (d,bb): per-group barrier
//     (agent-scope acq_rel atomic + acquire spin); launched cooperatively for residency
// Carried: att softmax over size-1 axis == 1 (weights dead); convs = NT-GEMMs over masked
// gru rows; numerics identical to round-5 path (h f32 carried, bf16 RNE at MFMA inputs).

#define T_SEQ 80

typedef __attribute__((ext_vector_type(8))) short short8;
typedef __attribute__((ext_vector_type(4))) float floatx4;

__device__ __forceinline__ float bf2f(unsigned short s) {
    union { unsigned int u; float f; } c; c.u = ((unsigned int)s) << 16; return c.f;
}
__device__ __forceinline__ unsigned short f2bf(float f) {
    union { float f; unsigned int u; } c; c.f = f;
    unsigned int u = c.u;
    u += 0x7fffu + ((u >> 16) & 1u);   // RNE
    return (unsigned short)(u >> 16);
}
// async global->LDS, 16B/lane; LDS dest wave-uniform base (HW scatters lane*16)
__device__ __forceinline__ void gld16(const unsigned short* g, unsigned short* lds_uniform) {
    __builtin_amdgcn_global_load_lds(
        (const __attribute__((address_space(1))) void*)g,
        (__attribute__((address_space(3))) void*)lds_uniform, 16, 0, 0);
}
// f32 source -> 8 bf16 into LDS (per-lane scatter via ds_write_b128)
__device__ __forceinline__ void stage8_f32(const float* __restrict__ src, unsigned short* __restrict__ dst) {
    float4 a = *(const float4*)src;
    float4 b = *(const float4*)(src + 4);
    short8 v;
    v[0] = (short)f2bf(a.x); v[1] = (short)f2bf(a.y); v[2] = (short)f2bf(a.z); v[3] = (short)f2bf(a.w);
    v[4] = (short)f2bf(b.x); v[5] = (short)f2bf(b.y); v[6] = (short)f2bf(b.z); v[7] = (short)f2bf(b.w);
    *(short8*)dst = v;
}

// ---------------------------------------------------------------------------
// MFMA bf16 NT-GEMM, dual-mode staging. C[m,n] = sum_k A[m,k]*B[n,k] (+bias[n]).
// (unchanged from round 5 — used for input projection, convs, map)
// ---------------------------------------------------------------------------
template<int AF32, int BF32, int OUTBF>
__global__ __launch_bounds__(256) void gemm_mfma(
    const void* __restrict__ Av, long a_base, int a_rpb, long a_bstride, int a_rstride,
    const void* __restrict__ B1v, const void* __restrict__ B2v,
    int n_split, int b_mod, long b_sa, long b_sb,
    const float* __restrict__ bias1, const float* __restrict__ bias2, int has_bias,
    void* __restrict__ Cout, long out_dsplit, long ldc,
    int kchunk, long zout)
{
    __shared__ __align__(16) unsigned short As[128 * 32];
    __shared__ __align__(16) unsigned short Bs[128 * 32];
    const int tid = threadIdx.x, wave = tid >> 6, lane = tid & 63;
    const int m0 = blockIdx.y * 128, n0 = blockIdx.x * 128;
    const long kbeg = (long)blockIdx.z * kchunk;

    const int c0 = wave * 64 + lane, c1 = 256 + c0;
    const int rA0 = c0 >> 2, pA0 = c0 & 3, rA1 = c1 >> 2, pA1 = c1 & 3;
    const int am0 = m0 + rA0, am1 = m0 + rA1;
    const long aoff0 = a_base + (long)(am0 / a_rpb) * a_bstride + (long)(am0 % a_rpb) * a_rstride + pA0 * 8 + kbeg;
    const long aoff1 = a_base + (long)(am1 / a_rpb) * a_bstride + (long)(am1 % a_rpb) * a_rstride + pA1 * 8 + kbeg;

    const int bn0 = n0 + rA0, bn1 = n0 + rA1;
    const int bd0 = (bn0 >= n_split), bd1 = (bn1 >= n_split);
    const int br0 = bn0 - (bd0 ? n_split : 0), br1 = bn1 - (bd1 ? n_split : 0);
    const long boff0 = (long)(br0 % b_mod) * b_sa + (long)(br0 / b_mod) * b_sb + pA0 * 8 + kbeg;
    const long boff1 = (long)(br1 % b_mod) * b_sa + (long)(br1 / b_mod) * b_sb + pA1 * 8 + kbeg;
    const void* Bp0 = bd0 ? B2v : B1v;
    const void* Bp1 = bd1 ? B2v : B1v;

    const int frow = lane & 15, fq = lane >> 4;
    const int wm = (wave >> 1) * 64, wn = (wave & 1) * 64;

    floatx4 acc[4][4];
    #pragma unroll
    for (int i = 0; i < 4; ++i)
        #pragma unroll
        for (int j = 0; j < 4; ++j) acc[i][j] = (floatx4)0.f;

    for (int k0 = 0; k0 < kchunk; k0 += 32) {
        if (AF32) {
            stage8_f32((const float*)Av + aoff0 + k0, As + c0 * 8);
            stage8_f32((const float*)Av + aoff1 + k0, As + c1 * 8);
        } else {
            gld16((const unsigned short*)Av + aoff0 + k0, As + (wave * 64) * 8);
            gld16((const unsigned short*)Av + aoff1 + k0, As + (256 + wave * 64) * 8);
        }
        if (BF32) {
            stage8_f32((const float*)Bp0 + boff0 + k0, Bs + c0 * 8);
            stage8_f32((const float*)Bp1 + boff1 + k0, Bs + c1 * 8);
        } else {
            gld16((const unsigned short*)Bp0 + boff0 + k0, Bs + (wave * 64) * 8);
            gld16((const unsigned short*)Bp1 + boff1 + k0, Bs + (256 + wave * 64) * 8);
        }
        __syncthreads();
        short8 af[4], bf[4];
        #pragma unroll
        for (int i = 0; i < 4; ++i) {
            af[i] = *(const short8*)&As[(wm + i * 16 + frow) * 32 + fq * 8];
            bf[i] = *(const short8*)&Bs[(wn + i * 16 + frow) * 32 + fq * 8];
        }
        #pragma unroll
        for (int mi = 0; mi < 4; ++mi)
            #pragma unroll
            for (int ni = 0; ni < 4; ++ni)
                acc[mi][ni] = __builtin_amdgcn_mfma_f32_16x16x32_bf16(af[mi], bf[ni], acc[mi][ni], 0, 0, 0);
        __syncthreads();
    }

    const long zoff = (long)blockIdx.z * zout;
    #pragma unroll
    for (int mi = 0; mi < 4; ++mi) {
        #pragma unroll
        for (int ni = 0; ni < 4; ++ni) {
            const int na = n0 + wn + ni * 16 + frow;
            const int dd = (na >= n_split);
            const int g  = na - (dd ? n_split : 0);
            float bv = has_bias ? (dd ? bias2 : bias1)[g] : 0.f;
            #pragma unroll
            for (int r = 0; r < 4; ++r) {
                const long gm = m0 + wm + mi * 16 + fq * 4 + r;
                const float v = acc[mi][ni][r] + bv;
                const long cidx = zoff + (dd ? out_dsplit : 0) + gm * ldc + g;
                if (OUTBF) ((unsigned short*)Cout)[cidx] = f2bf(v);
                else       ((float*)Cout)[cidx] = v;
            }
        }
    }
}

// ---------------------------------------------------------------------------
// Persistent fused GRU scan. Grid (cc=16, bb=4, d=2) = 128 blocks x 256 thr.
// Per block: Whh slice (3 gates x 32 cols x 512 K bf16) resident in LDS; per step
// C[32 rows x 96 gates] = hbf[rows][512] @ Whh_slice^T via 16x16x32 MFMA
// (4 waves, wave tile 16x48), gate update fused, h f32 in registers.
// Cross-block handoff: hbf2 double buffer; 16-block (d,bb)-group barrier per step.
// hbf2 buf0 and counters must be zeroed before launch.
// ---------------------------------------------------------------------------
__global__ __launch_bounds__(256) void k_gru_scan(
    const unsigned short* __restrict__ pre,      // [2][10240][1536] bf16
    unsigned short* __restrict__ hbf2,           // [2 buf][2 dir][128][512] bf16
    unsigned short* __restrict__ Mp,             // [128][88][1024] bf16
    unsigned int* __restrict__ counters,         // [8], zeroed
    const float* __restrict__ Whh_f, const float* __restrict__ Whh_b,
    const float* __restrict__ bhh_f, const float* __restrict__ bhh_b)
{
    __shared__ __align__(16) unsigned short Wlds[96][520];  // 99,840 B; pad 520: stride 1040 B -> 2-way (free)
    __shared__ float ghl[32][99];                           // 12,672 B; stride 99 -> <=2-way on both sides
    __shared__ float bhl[96];

    const int tid = threadIdx.x, wave = tid >> 6, lane = tid & 63;
    const int cc = blockIdx.x, bb = blockIdx.y, d = blockIdx.z;
    const int c0 = cc * 32;
    const float* WhhD = d ? Whh_b : Whh_f;
    const float* bhhD = d ? bhh_b : bhh_f;

    // prologue: Whh slice -> LDS bf16 (RNE, same values k_whh_prep produced)
    for (int e = tid; e < 6144; e += 256) {
        const int r = e >> 6, p = e & 63;          // r = g*32 + j'
        const int g = r >> 5, jp = r & 31;
        stage8_f32(WhhD + ((long)(g * 512 + c0 + jp)) * 512 + p * 8, &Wlds[r][p * 8]);
    }
    if (tid < 96) bhl[tid] = bhhD[(tid >> 5) * 512 + c0 + (tid & 31)];

    const int frow = lane & 15, fq = lane >> 4;
    const int wm = (wave & 1) * 16, wn = (wave >> 1) * 48;
    const long arow = (long)(bb * 32 + wm + frow) * 512 + fq * 8;

    // gate-phase ownership: thread -> (row=tid>>3, 4 consecutive j' at (tid&7)*4)
    const int grow = tid >> 3, gj = (tid & 7) * 4;
    const long bglob = bb * 32 + grow;
    float hreg[4] = {0.f, 0.f, 0.f, 0.f};        // h f32 carried in registers
    unsigned int* cnt = counters + (d * 4 + bb);

    __syncthreads();

    #pragma unroll 1
    for (int t = 0; t < T_SEQ; ++t) {
        const int ti = d ? (T_SEQ - 1 - t) : t;
        const unsigned short* hread = hbf2 + ((t & 1) * 2 + d) * 65536;

        // A fragments (16 rows x full K=512) global->reg, issued first
        short8 af[16];
        #pragma unroll
        for (int kk = 0; kk < 16; ++kk)
            af[kk] = *(const short8*)(hread + arow + kk * 32);

        // pre prefetch (h-independent) overlapped with MFMA phase
        const unsigned short* pb = pre + (long)d * 15728640 + (bglob * T_SEQ + ti) * 1536 + c0 + gj;
        const ushort4 pv0 = *(const ushort4*)pb;
        const ushort4 pv1 = *(const ushort4*)(pb + 512);
        const ushort4 pv2 = *(const ushort4*)(pb + 1024);

        floatx4 acc[3] = {(floatx4)0.f, (floatx4)0.f, (floatx4)0.f};
        #pragma unroll
        for (int kk = 0; kk < 16; ++kk) {
            #pragma unroll
            for (int n = 0; n < 3; ++n) {
                const short8 bf = *(const short8*)&Wlds[wn + n * 16 + frow][kk * 32 + fq * 8];
                acc[n] = __builtin_amdgcn_mfma_f32_16x16x32_bf16(af[kk], bf, acc[n], 0, 0, 0);
            }
        }
        #pragma unroll
        for (int n = 0; n < 3; ++n)
            #pragma unroll
            for (int r = 0; r < 4; ++r)
                ghl[wm + fq * 4 + r][wn + n * 16 + frow] = acc[n][r];
        __syncthreads();

        // fused gate update (identical math to k_gru_gate)
        ushort4 hv;
        #pragma unroll
        for (int i = 0; i < 4; ++i) {
            const int jp = gj + i;
            const float gr = ghl[grow][jp]      + bhl[jp];
            const float gz = ghl[grow][32 + jp] + bhl[32 + jp];
            const float gn = ghl[grow][64 + jp] + bhl[64 + jp];
            const float rr = 1.f / (1.f + expf(-(bf2f(((const unsigned short*)&pv0)[i]) + gr)));
            const float zz = 1.f / (1.f + expf(-(bf2f(((const unsigned short*)&pv1)[i]) + gz)));
            const float nn = tanhf(bf2f(((const unsigned short*)&pv2)[i]) + rr * gn);
            const float hnew = (1.f - zz) * nn + zz * hreg[i];
            hreg[i] = hnew;
            ((unsigned short*)&hv)[i] = f2bf(hnew);
        }
        unsigned short* hw = hbf2 + (((t + 1) & 1) * 2 + d) * 65536;
        *(ushort4*)(hw + bglob * 512 + c0 + gj) = hv;
        *(ushort4*)(Mp + bglob * 90112 + (long)(4 + ti) * 1024 + d * 512 + c0 + gj) = hv;

        // (d,bb)-group barrier: release my h writes, acquire peers'. Monotonic counter.
        __syncthreads();   // drains vmcnt -> stores at L2 before the release below
        if (tid == 0) {
            __hip_atomic_fetch_add(cnt, 1u, __ATOMIC_ACQ_REL, __HIP_MEMORY_SCOPE_AGENT);
            const unsigned int target = (unsigned int)(t + 1) * 16u;
            while (__hip_atomic_load(cnt, __ATOMIC_ACQUIRE, __HIP_MEMORY_SCOPE_AGENT) < target)
                __builtin_amdgcn_s_sleep(2);
        }
        __syncthreads();
    }
}

// Mask Mp in place (bf16 * {0,1} lossless) and mean over valid steps. mask is f32.
__global__ __launch_bounds__(256) void k_mask_mean(
    unsigned short* __restrict__ Mp, const float* __restrict__ mask,
    const int* __restrict__ lengths, float* __restrict__ mean)
{
    const int b = blockIdx.y;
    const int c = blockIdx.x * 256 + threadIdx.x;
    float acc = 0.f;
    unsigned short* base = Mp + (long)b * 90112 + 4096 + c;
    for (int t = 0; t < T_SEQ; ++t) {
        float m = mask[b * T_SEQ + t];
        float v = bf2f(base[t * 1024]) * m;
        base[t * 1024] = f2bf(v);
        acc += v;
    }
    mean[b * 1024 + c] = acc / (float)lengths[b];
}

// Conv epilogue over bf16 D: c[b,kf,t] = sum_i D[b, t-w+1+i, i*512+kf]; relu(bias+max_t).
__global__ __launch_bounds__(256) void k_conv_epi(
    const unsigned short* __restrict__ D, const float* __restrict__ cb,
    float* __restrict__ con, int w, int widx)
{
    const int b  = blockIdx.y;
    const int kf = blockIdx.x * 256 + threadIdx.x;
    const int N  = w * 512;
    const unsigned short* Db = D + (long)b * T_SEQ * N;
    float mx = -1e30f;
    for (int t = 0; t < T_SEQ + w - 1; ++t) {
        float s = 0.f;
        for (int i = 0; i < w; ++i) {
            int tau = t - w + 1 + i;
            if (tau >= 0 && tau < T_SEQ) s += bf2f(Db[(long)tau * N + i * 512 + kf]);
        }
        mx = fmaxf(mx, s);
    }
    con[b * 2048 + widx * 512 + kf] = fmaxf(0.f, mx + cb[kf]);
}

// Assemble map input (bf16 for MFMA map GEMM): [mean | con | videos_origin(f32)].
__global__ __launch_bounds__(256) void k_gather(
    const float* __restrict__ mean, const float* __restrict__ con,
    const float* __restrict__ vo, unsigned short* __restrict__ fin)
{
    int e = blockIdx.x * 256 + threadIdx.x;     // < 655360
    int b = e / 5120, k = e - b * 5120;
    float v;
    if (k < 1024)      v = mean[b * 1024 + k];
    else if (k < 3072) v = con[b * 2048 + (k - 1024)];
    else               v = vo[b * 2048 + (k - 3072)];
    fin[e] = f2bf(v);
}

// Reduce split-K partials + bias (f32) -> feat.
__global__ __launch_bounds__(256) void k_map_reduce(
    const float* __restrict__ part, const float* __restrict__ map_b,
    float* __restrict__ feat)
{
    int e = blockIdx.x * 256 + threadIdx.x;     // < 262144
    float s = map_b[e & 2047];
    #pragma unroll
    for (int z = 0; z < 8; ++z) s += part[(long)z * 262144 + e];
    feat[e] = s;
}

// BN (eval: /sqrt(1+eps)*gamma+beta) + row L2-normalize -> f32 out.
__global__ __launch_bounds__(256) void k_bn_norm(
    const float* __restrict__ feat, const float* __restrict__ gamma,
    const float* __restrict__ beta, float* __restrict__ out)
{
    const int b = blockIdx.x, tid = threadIdx.x;
    const float inv_c = 1.f / sqrtf(1.f + 1e-5f);
    float y[8]; float ss = 0.f;
    #pragma unroll
    for (int u = 0; u < 8; ++u) {
        int o = u * 256 + tid;
        float v = feat[b * 2048 + o] * inv_c * gamma[o] + beta[o];
        y[u] = v; ss += v * v;
    }
    #pragma unroll
    for (int off = 32; off >= 1; off >>= 1) ss += __shfl_down(ss, off, 64);
    __shared__ float rs[4];
    if ((tid & 63) == 0) rs[tid >> 6] = ss;
    __syncthreads();
    float rn = 1.f / sqrtf(rs[0] + rs[1] + rs[2] + rs[3]);
    #pragma unroll
    for (int u = 0; u < 8; ++u) {
        int o = u * 256 + tid;
        out[b * 2048 + o] = y[u] * rn;
    }
}

extern "C" void kernel_launch(void* const* d_in, const int* in_sizes, int n_in,
                              void* d_out, int out_size, void* d_ws, size_t ws_size,
                              hipStream_t stream)
{
    const float* videos  = (const float*)d_in[0];
    const float* vorigin = (const float*)d_in[1];
    const int*   lengths = (const int*)d_in[2];
    const float* mask    = (const float*)d_in[3];
    // d_in[4] gru_text_out: unused by the reference
    const float* Wih_f = (const float*)d_in[5];
    const float* Whh_f = (const float*)d_in[6];
    const float* bih_f = (const float*)d_in[7];
    const float* bhh_f = (const float*)d_in[8];
    const float* Wih_b = (const float*)d_in[9];
    const float* Whh_b = (const float*)d_in[10];
    const float* bih_b = (const float*)d_in[11];
    const float* bhh_b = (const float*)d_in[12];
    // d_in[13..16] attention: dead (softmax over size-1 axis == 1)
    const float* cw[4] = { (const float*)d_in[17], (const float*)d_in[19],
                           (const float*)d_in[21], (const float*)d_in[23] };
    const float* cb[4] = { (const float*)d_in[18], (const float*)d_in[20],
                           (const float*)d_in[22], (const float*)d_in[24] };
    const float* map_W = (const float*)d_in[25];
    const float* map_b = (const float*)d_in[26];
    const float* gamma = (const float*)d_in[27];
    const float* beta  = (const float*)d_in[28];

    // --- workspace layout (bytes) ---
    unsigned char* W = (unsigned char*)d_ws;
    unsigned short* pre    = (unsigned short*)W;               // [2][10240][1536] bf16 (conv D + map part alias)
    unsigned short* Mp     = (unsigned short*)(W + 62914560);  // [128][88][1024] bf16 (pad rows never read)
    unsigned short* hbf2   = (unsigned short*)(W + 85983232);  // [2 buf][2 dir][128][512] bf16 (524,288 B)
    unsigned int*   counters = (unsigned int*)(W + 86507520);  // [8] group barrier counters
    float*          mean   = (float*)(W + 88342528);           // [128][1024] f32
    float*          con    = (float*)(W + 88866816);           // [128][2048] f32
    unsigned short* fin    = (unsigned short*)(W + 89915392);  // [128][5120] bf16
    float*          feat   = (float*)(W + 91226112);           // [128][2048] f32
    float*          part   = (float*)W;                        // [8][128][2048] f32, aliases pre (dead then)

    // zero hbf2 (t=0 reads buf0 = h(0)=0) and the barrier counters (every replay)
    hipMemsetAsync(W + 85983232, 0, 524288 + 32, stream);

    // GRU input projection: pre[d][b*80+t][1536] = videos @ Wih_d^T + bih_d (bf16 out)
    gemm_mfma<1, 1, 1><<<dim3(24, 80, 1), 256, 0, stream>>>(
        videos, 0l, 10240, 0l, 2048,
        Wih_f, Wih_b, 1536, 1536, 2048l, 0l,
        bih_f, bih_b, 1,
        pre, 15728640l, 1536l, 2048, 0l);

    // Fused persistent GRU scan: one cooperative launch replaces 160 kernels.
    {
        void* args[] = { (void*)&pre, (void*)&hbf2, (void*)&Mp, (void*)&counters,
                         (void*)&Whh_f, (void*)&Whh_b, (void*)&bhh_f, (void*)&bhh_b };
        hipLaunchCooperativeKernel((const void*)k_gru_scan, dim3(16, 4, 2),
                                   dim3(256, 1, 1), args, 0, stream);
    }

    k_mask_mean<<<dim3(4, 128), 256, 0, stream>>>(Mp, mask, lengths, mean);

    // Convs: D[(b,tau),(i*512+kf)] = sum_d Mp[b,tau,d]*cw[kf,i,d] (bf16 D into pre region)
    for (int wi = 0; wi < 4; ++wi) {
        int ww = wi + 2;
        int N  = ww * 512;
        gemm_mfma<0, 1, 1><<<dim3(N / 128, 80, 1), 256, 0, stream>>>(
            Mp, 4096l, 80, 90112l, 1024,
            cw[wi], nullptr, 1 << 30, 512, (long)(ww * 1024), 1024l,
            nullptr, nullptr, 0,
            pre, 0l, (long)N, 1024, 0l);
        k_conv_epi<<<dim3(2, 128), 256, 0, stream>>>(pre, cb[wi], con, ww, wi);
    }

    k_gather<<<2560, 256, 0, stream>>>(mean, con, vorigin, fin);

    // map: split-K=8 MFMA GEMM -> f32 partials (alias pre), then reduce + bias.
    gemm_mfma<0, 1, 0><<<dim3(16, 1, 8), 256, 0, stream>>>(
        fin, 0l, 128, 0l, 5120,
        map_W, nullptr, 1 << 30, 2048, 5120l, 0l,
        nullptr, nullptr, 0,
        part, 0l, 2048l, 640, 262144l);
    k_map_reduce<<<1024, 256, 0, stream>>>(part, map_b, feat);

    k_bn_norm<<<128, 256, 0, stream>>>(feat, gamma, beta, (float*)d_out);
}

// Round 2
// 1747.949 us; speedup vs baseline: 1.4001x; 1.3336x over previous
//
#include <hip/hip_runtime.h>
#include <hip/hip_bf16.h>

// Video_multilevel_encoding — round 7: fence-free GRU scan exchange.
// Round-6 post-mortem: scan = 13.3 µs/step, latency-bound (MfmaUtil 1.2%). Causes:
// (a) 8 barrier counters in ONE cache line -> cross-XCD ping-pong on every add/spin;
// (b) acquire/release fences per step -> per-poll cache invalidates + L2 writebacks,
//     killing pre/Whh caching.
// This round: h exchange via RELAXED agent-scope atomics (coherent per-op, no fences,
// no invalidates; ordering by vmcnt(0)-drain before the relaxed counter add), counters
// padded to 256B, XCD-aware group placement (group gid = bx&7 -> one XCD), gate update
// fully register-local (3 gate accumulators per thread, ghl LDS round-trip deleted),
// pre prefetched for t+1 before the barrier.

#define T_SEQ 80

typedef __attribute__((ext_vector_type(8))) short short8;
typedef __attribute__((ext_vector_type(4))) float floatx4;

__device__ __forceinline__ float bf2f(unsigned short s) {
    union { unsigned int u; float f; } c; c.u = ((unsigned int)s) << 16; return c.f;
}
__device__ __forceinline__ unsigned short f2bf(float f) {
    union { float f; unsigned int u; } c; c.f = f;
    unsigned int u = c.u;
    u += 0x7fffu + ((u >> 16) & 1u);   // RNE
    return (unsigned short)(u >> 16);
}
// async global->LDS, 16B/lane; LDS dest wave-uniform base (HW scatters lane*16)
__device__ __forceinline__ void gld16(const unsigned short* g, unsigned short* lds_uniform) {
    __builtin_amdgcn_global_load_lds(
        (const __attribute__((address_space(1))) void*)g,
        (__attribute__((address_space(3))) void*)lds_uniform, 16, 0, 0);
}
// f32 source -> 8 bf16 into LDS (per-lane scatter via ds_write_b128)
__device__ __forceinline__ void stage8_f32(const float* __restrict__ src, unsigned short* __restrict__ dst) {
    float4 a = *(const float4*)src;
    float4 b = *(const float4*)(src + 4);
    short8 v;
    v[0] = (short)f2bf(a.x); v[1] = (short)f2bf(a.y); v[2] = (short)f2bf(a.z); v[3] = (short)f2bf(a.w);
    v[4] = (short)f2bf(b.x); v[5] = (short)f2bf(b.y); v[6] = (short)f2bf(b.z); v[7] = (short)f2bf(b.w);
    *(short8*)dst = v;
}

// ---------------------------------------------------------------------------
// MFMA bf16 NT-GEMM, dual-mode staging. C[m,n] = sum_k A[m,k]*B[n,k] (+bias[n]).
// (unchanged — used for input projection, convs, map)
// ---------------------------------------------------------------------------
template<int AF32, int BF32, int OUTBF>
__global__ __launch_bounds__(256) void gemm_mfma(
    const void* __restrict__ Av, long a_base, int a_rpb, long a_bstride, int a_rstride,
    const void* __restrict__ B1v, const void* __restrict__ B2v,
    int n_split, int b_mod, long b_sa, long b_sb,
    const float* __restrict__ bias1, const float* __restrict__ bias2, int has_bias,
    void* __restrict__ Cout, long out_dsplit, long ldc,
    int kchunk, long zout)
{
    __shared__ __align__(16) unsigned short As[128 * 32];
    __shared__ __align__(16) unsigned short Bs[128 * 32];
    const int tid = threadIdx.x, wave = tid >> 6, lane = tid & 63;
    const int m0 = blockIdx.y * 128, n0 = blockIdx.x * 128;
    const long kbeg = (long)blockIdx.z * kchunk;

    const int c0 = wave * 64 + lane, c1 = 256 + c0;
    const int rA0 = c0 >> 2, pA0 = c0 & 3, rA1 = c1 >> 2, pA1 = c1 & 3;
    const int am0 = m0 + rA0, am1 = m0 + rA1;
    const long aoff0 = a_base + (long)(am0 / a_rpb) * a_bstride + (long)(am0 % a_rpb) * a_rstride + pA0 * 8 + kbeg;
    const long aoff1 = a_base + (long)(am1 / a_rpb) * a_bstride + (long)(am1 % a_rpb) * a_rstride + pA1 * 8 + kbeg;

    const int bn0 = n0 + rA0, bn1 = n0 + rA1;
    const int bd0 = (bn0 >= n_split), bd1 = (bn1 >= n_split);
    const int br0 = bn0 - (bd0 ? n_split : 0), br1 = bn1 - (bd1 ? n_split : 0);
    const long boff0 = (long)(br0 % b_mod) * b_sa + (long)(br0 / b_mod) * b_sb + pA0 * 8 + kbeg;
    const long boff1 = (long)(br1 % b_mod) * b_sa + (long)(br1 / b_mod) * b_sb + pA1 * 8 + kbeg;
    const void* Bp0 = bd0 ? B2v : B1v;
    const void* Bp1 = bd1 ? B2v : B1v;

    const int frow = lane & 15, fq = lane >> 4;
    const int wm = (wave >> 1) * 64, wn = (wave & 1) * 64;

    floatx4 acc[4][4];
    #pragma unroll
    for (int i = 0; i < 4; ++i)
        #pragma unroll
        for (int j = 0; j < 4; ++j) acc[i][j] = (floatx4)0.f;

    for (int k0 = 0; k0 < kchunk; k0 += 32) {
        if (AF32) {
            stage8_f32((const float*)Av + aoff0 + k0, As + c0 * 8);
            stage8_f32((const float*)Av + aoff1 + k0, As + c1 * 8);
        } else {
            gld16((const unsigned short*)Av + aoff0 + k0, As + (wave * 64) * 8);
            gld16((const unsigned short*)Av + aoff1 + k0, As + (256 + wave * 64) * 8);
        }
        if (BF32) {
            stage8_f32((const float*)Bp0 + boff0 + k0, Bs + c0 * 8);
            stage8_f32((const float*)Bp1 + boff1 + k0, Bs + c1 * 8);
        } else {
            gld16((const unsigned short*)Bp0 + boff0 + k0, Bs + (wave * 64) * 8);
            gld16((const unsigned short*)Bp1 + boff1 + k0, Bs + (256 + wave * 64) * 8);
        }
        __syncthreads();
        short8 af[4], bf[4];
        #pragma unroll
        for (int i = 0; i < 4; ++i) {
            af[i] = *(const short8*)&As[(wm + i * 16 + frow) * 32 + fq * 8];
            bf[i] = *(const short8*)&Bs[(wn + i * 16 + frow) * 32 + fq * 8];
        }
        #pragma unroll
        for (int mi = 0; mi < 4; ++mi)
            #pragma unroll
            for (int ni = 0; ni < 4; ++ni)
                acc[mi][ni] = __builtin_amdgcn_mfma_f32_16x16x32_bf16(af[mi], bf[ni], acc[mi][ni], 0, 0, 0);
        __syncthreads();
    }

    const long zoff = (long)blockIdx.z * zout;
    #pragma unroll
    for (int mi = 0; mi < 4; ++mi) {
        #pragma unroll
        for (int ni = 0; ni < 4; ++ni) {
            const int na = n0 + wn + ni * 16 + frow;
            const int dd = (na >= n_split);
            const int g  = na - (dd ? n_split : 0);
            float bv = has_bias ? (dd ? bias2 : bias1)[g] : 0.f;
            #pragma unroll
            for (int r = 0; r < 4; ++r) {
                const long gm = m0 + wm + mi * 16 + fq * 4 + r;
                const float v = acc[mi][ni][r] + bv;
                const long cidx = zoff + (dd ? out_dsplit : 0) + gm * ldc + g;
                if (OUTBF) ((unsigned short*)Cout)[cidx] = f2bf(v);
                else       ((float*)Cout)[cidx] = v;
            }
        }
    }
}

// ---------------------------------------------------------------------------
// Persistent fused GRU scan, fence-free exchange. Grid (128,1,1) x 256 thr.
// Block bx: gid = bx&7 (group = (d,bb), all 16 members on one XCD under round-robin),
// cc = bx>>3 (32 h-cols). Wave tile: 16 rows x 16 cols x 3 gate accs -> gate update
// is register-local. h handoff: relaxed agent-scope atomic u64 loads / u32 stores
// (no fences, no cache invalidates); barrier = padded relaxed counter; ordering by
// the vmcnt(0) drain __syncthreads performs before the leader's add.
// ---------------------------------------------------------------------------
__global__ __launch_bounds__(256) void k_gru_scan(
    const unsigned short* __restrict__ pre,      // [2][10240][1536] bf16
    unsigned short* __restrict__ hbf2,           // [2 buf][2 dir][128][512] bf16
    unsigned short* __restrict__ Mp,             // [128][88][1024] bf16
    unsigned int* __restrict__ counters,         // [8][64] (256B-padded), zeroed
    const float* __restrict__ Whh_f, const float* __restrict__ Whh_b,
    const float* __restrict__ bhh_f, const float* __restrict__ bhh_b)
{
    __shared__ __align__(16) unsigned short Wlds[96][520];  // 99,840 B

    const int tid = threadIdx.x, wave = tid >> 6, lane = tid & 63;
    const int bx = blockIdx.x;
    const int cc = bx >> 3, gid = bx & 7;        // group gid -> one XCD (perf heuristic)
    const int d = gid >> 2, bb = gid & 3;
    const int c0 = cc * 32;
    const float* WhhD = d ? Whh_b : Whh_f;
    const float* bhhD = d ? bhh_b : bhh_f;

    // prologue: Whh slice (3 gates x 32 cols x 512 K) -> LDS bf16 (RNE)
    for (int e = tid; e < 6144; e += 256) {
        const int r = e >> 6, p = e & 63;        // r = g*32 + jp
        const int g = r >> 5, jp = r & 31;
        stage8_f32(WhhD + ((long)(g * 512 + c0 + jp)) * 512 + p * 8, &Wlds[r][p * 8]);
    }

    const int frow = lane & 15, fq = lane >> 4;
    const int wr = wave & 1, wc = wave >> 1;
    const int myc = c0 + wc * 16 + frow;             // owned h col in [0,512)
    const int row0 = bb * 32 + wr * 16 + fq * 4;     // owned batch rows row0..row0+3
    const long arow = (long)(bb * 32 + wr * 16 + frow) * 512 + fq * 8;

    float bres[3];
    #pragma unroll
    for (int g = 0; g < 3; ++g) bres[g] = bhhD[g * 512 + myc];

    float hreg[4] = {0.f, 0.f, 0.f, 0.f};           // h f32 carried in registers
    unsigned int* cnt = counters + gid * 64;

    // pre for t=0
    float pv[3][4];
    {
        const int ti0 = d ? (T_SEQ - 1) : 0;
        #pragma unroll
        for (int q = 0; q < 4; ++q) {
            const unsigned short* pb = pre + (long)d * 15728640 + ((long)(row0 + q) * T_SEQ + ti0) * 1536 + myc;
            pv[0][q] = bf2f(pb[0]); pv[1][q] = bf2f(pb[512]); pv[2][q] = bf2f(pb[1024]);
        }
    }

    __syncthreads();   // Wlds ready

    #pragma unroll 1
    for (int t = 0; t < T_SEQ; ++t) {
        const int ti = d ? (T_SEQ - 1 - t) : t;
        const unsigned short* hread = hbf2 + ((t & 1) * 2 + d) * 65536;

        // A fragments: 16 rows x K=512 via relaxed agent atomic u64 (coherent, no fence)
        short8 af[16];
        #pragma unroll
        for (int kk = 0; kk < 16; ++kk) {
            union { unsigned long long u[2]; short8 s; } cv;
            unsigned long long* p = (unsigned long long*)(hread + arow + kk * 32);
            cv.u[0] = __hip_atomic_load(p,     __ATOMIC_RELAXED, __HIP_MEMORY_SCOPE_AGENT);
            cv.u[1] = __hip_atomic_load(p + 1, __ATOMIC_RELAXED, __HIP_MEMORY_SCOPE_AGENT);
            af[kk] = cv.s;
        }

        floatx4 acc[3] = {(floatx4)0.f, (floatx4)0.f, (floatx4)0.f};
        #pragma unroll
        for (int kk = 0; kk < 16; ++kk) {
            #pragma unroll
            for (int g = 0; g < 3; ++g) {
                const short8 bfr = *(const short8*)&Wlds[g * 32 + wc * 16 + frow][kk * 32 + fq * 8];
                acc[g] = __builtin_amdgcn_mfma_f32_16x16x32_bf16(af[kk], bfr, acc[g], 0, 0, 0);
            }
        }

        // gate update, fully in registers (identical math to round-5 path)
        unsigned long long hv4 = 0ull;               // q-th bf16 at bits [16q,16q+16)
        #pragma unroll
        for (int q = 0; q < 4; ++q) {
            const float gr = acc[0][q] + bres[0];
            const float gz = acc[1][q] + bres[1];
            const float gn = acc[2][q] + bres[2];
            const float rr = 1.f / (1.f + expf(-(pv[0][q] + gr)));
            const float zz = 1.f / (1.f + expf(-(pv[1][q] + gz)));
            const float nn = tanhf(pv[2][q] + rr * gn);
            const float hnew = (1.f - zz) * nn + zz * hreg[q];
            hreg[q] = hnew;
            hv4 |= (unsigned long long)f2bf(hnew) << (16 * q);
        }

        // pair adjacent cols (lanes frow 2i/2i+1) -> packed u32 stores, 2 rows each
        const unsigned long long prt = __shfl_xor(hv4, 1, 64);
        const int even = ((frow & 1) == 0);
        const int cpair = myc & ~1;
        unsigned short* hw = hbf2 + (((t + 1) & 1) * 2 + d) * 65536;
        #pragma unroll
        for (int s = 0; s < 2; ++s) {
            const int q = even ? s : (2 + s);
            const unsigned int lo = (unsigned int)((even ? hv4 : prt) >> (16 * q)) & 0xffffu;
            const unsigned int hi = (unsigned int)((even ? prt : hv4) >> (16 * q)) & 0xffffu;
            const unsigned int pk = lo | (hi << 16);
            const long rowg = row0 + q;
            __hip_atomic_store((unsigned int*)(hw + rowg * 512 + cpair), pk,
                               __ATOMIC_RELAXED, __HIP_MEMORY_SCOPE_AGENT);
            *(unsigned int*)(Mp + rowg * 90112 + (long)(4 + ti) * 1024 + d * 512 + cpair) = pk;
        }

        // pre prefetch for t+1 (h-independent) before the barrier
        if (t + 1 < T_SEQ) {
            const int tn = d ? (T_SEQ - 2 - t) : (t + 1);
            #pragma unroll
            for (int q = 0; q < 4; ++q) {
                const unsigned short* pb = pre + (long)d * 15728640 + ((long)(row0 + q) * T_SEQ + tn) * 1536 + myc;
                pv[0][q] = bf2f(pb[0]); pv[1][q] = bf2f(pb[512]); pv[2][q] = bf2f(pb[1024]);
            }
        }

        // group barrier: syncthreads drains vmcnt(0) -> h stores acked at coherence
        // point before the relaxed add; peers observing counter observe h.
        __syncthreads();
        if (tid == 0) {
            __hip_atomic_fetch_add(cnt, 1u, __ATOMIC_RELAXED, __HIP_MEMORY_SCOPE_AGENT);
            const unsigned int target = (unsigned int)(t + 1) * 16u;
            while (__hip_atomic_load(cnt, __ATOMIC_RELAXED, __HIP_MEMORY_SCOPE_AGENT) < target)
                __builtin_amdgcn_s_sleep(1);
        }
        __syncthreads();
    }
}

// Mask Mp in place (bf16 * {0,1} lossless) and mean over valid steps. mask is f32.
__global__ __launch_bounds__(256) void k_mask_mean(
    unsigned short* __restrict__ Mp, const float* __restrict__ mask,
    const int* __restrict__ lengths, float* __restrict__ mean)
{
    const int b = blockIdx.y;
    const int c = blockIdx.x * 256 + threadIdx.x;
    float acc = 0.f;
    unsigned short* base = Mp + (long)b * 90112 + 4096 + c;
    for (int t = 0; t < T_SEQ; ++t) {
        float m = mask[b * T_SEQ + t];
        float v = bf2f(base[t * 1024]) * m;
        base[t * 1024] = f2bf(v);
        acc += v;
    }
    mean[b * 1024 + c] = acc / (float)lengths[b];
}

// Conv epilogue over bf16 D: c[b,kf,t] = sum_i D[b, t-w+1+i, i*512+kf]; relu(bias+max_t).
__global__ __launch_bounds__(256) void k_conv_epi(
    const unsigned short* __restrict__ D, const float* __restrict__ cb,
    float* __restrict__ con, int w, int widx)
{
    const int b  = blockIdx.y;
    const int kf = blockIdx.x * 256 + threadIdx.x;
    const int N  = w * 512;
    const unsigned short* Db = D + (long)b * T_SEQ * N;
    float mx = -1e30f;
    for (int t = 0; t < T_SEQ + w - 1; ++t) {
        float s = 0.f;
        for (int i = 0; i < w; ++i) {
            int tau = t - w + 1 + i;
            if (tau >= 0 && tau < T_SEQ) s += bf2f(Db[(long)tau * N + i * 512 + kf]);
        }
        mx = fmaxf(mx, s);
    }
    con[b * 2048 + widx * 512 + kf] = fmaxf(0.f, mx + cb[kf]);
}

// Assemble map input (bf16 for MFMA map GEMM): [mean | con | videos_origin(f32)].
__global__ __launch_bounds__(256) void k_gather(
    const float* __restrict__ mean, const float* __restrict__ con,
    const float* __restrict__ vo, unsigned short* __restrict__ fin)
{
    int e = blockIdx.x * 256 + threadIdx.x;     // < 655360
    int b = e / 5120, k = e - b * 5120;
    float v;
    if (k < 1024)      v = mean[b * 1024 + k];
    else if (k < 3072) v = con[b * 2048 + (k - 1024)];
    else               v = vo[b * 2048 + (k - 3072)];
    fin[e] = f2bf(v);
}

// Reduce split-K partials + bias (f32) -> feat.
__global__ __launch_bounds__(256) void k_map_reduce(
    const float* __restrict__ part, const float* __restrict__ map_b,
    float* __restrict__ feat)
{
    int e = blockIdx.x * 256 + threadIdx.x;     // < 262144
    float s = map_b[e & 2047];
    #pragma unroll
    for (int z = 0; z < 8; ++z) s += part[(long)z * 262144 + e];
    feat[e] = s;
}

// BN (eval: /sqrt(1+eps)*gamma+beta) + row L2-normalize -> f32 out.
__global__ __launch_bounds__(256) void k_bn_norm(
    const float* __restrict__ feat, const float* __restrict__ gamma,
    const float* __restrict__ beta, float* __restrict__ out)
{
    const int b = blockIdx.x, tid = threadIdx.x;
    const float inv_c = 1.f / sqrtf(1.f + 1e-5f);
    float y[8]; float ss = 0.f;
    #pragma unroll
    for (int u = 0; u < 8; ++u) {
        int o = u * 256 + tid;
        float v = feat[b * 2048 + o] * inv_c * gamma[o] + beta[o];
        y[u] = v; ss += v * v;
    }
    #pragma unroll
    for (int off = 32; off >= 1; off >>= 1) ss += __shfl_down(ss, off, 64);
    __shared__ float rs[4];
    if ((tid & 63) == 0) rs[tid >> 6] = ss;
    __syncthreads();
    float rn = 1.f / sqrtf(rs[0] + rs[1] + rs[2] + rs[3]);
    #pragma unroll
    for (int u = 0; u < 8; ++u) {
        int o = u * 256 + tid;
        out[b * 2048 + o] = y[u] * rn;
    }
}

extern "C" void kernel_launch(void* const* d_in, const int* in_sizes, int n_in,
                              void* d_out, int out_size, void* d_ws, size_t ws_size,
                              hipStream_t stream)
{
    const float* videos  = (const float*)d_in[0];
    const float* vorigin = (const float*)d_in[1];
    const int*   lengths = (const int*)d_in[2];
    const float* mask    = (const float*)d_in[3];
    // d_in[4] gru_text_out: unused by the reference
    const float* Wih_f = (const float*)d_in[5];
    const float* Whh_f = (const float*)d_in[6];
    const float* bih_f = (const float*)d_in[7];
    const float* bhh_f = (const float*)d_in[8];
    const float* Wih_b = (const float*)d_in[9];
    const float* Whh_b = (const float*)d_in[10];
    const float* bih_b = (const float*)d_in[11];
    const float* bhh_b = (const float*)d_in[12];
    // d_in[13..16] attention: dead (softmax over size-1 axis == 1)
    const float* cw[4] = { (const float*)d_in[17], (const float*)d_in[19],
                           (const float*)d_in[21], (const float*)d_in[23] };
    const float* cb[4] = { (const float*)d_in[18], (const float*)d_in[20],
                           (const float*)d_in[22], (const float*)d_in[24] };
    const float* map_W = (const float*)d_in[25];
    const float* map_b = (const float*)d_in[26];
    const float* gamma = (const float*)d_in[27];
    const float* beta  = (const float*)d_in[28];

    // --- workspace layout (bytes) ---
    unsigned char* W = (unsigned char*)d_ws;
    unsigned short* pre    = (unsigned short*)W;               // [2][10240][1536] bf16 (conv D + map part alias)
    unsigned short* Mp     = (unsigned short*)(W + 62914560);  // [128][88][1024] bf16 (pad rows never read)
    unsigned short* hbf2   = (unsigned short*)(W + 85983232);  // [2 buf][2 dir][128][512] bf16 (524,288 B)
    unsigned int*   counters = (unsigned int*)(W + 86507520);  // [8][64] padded barrier counters (2048 B)
    float*          mean   = (float*)(W + 88342528);           // [128][1024] f32
    float*          con    = (float*)(W + 88866816);           // [128][2048] f32
    unsigned short* fin    = (unsigned short*)(W + 89915392);  // [128][5120] bf16
    float*          feat   = (float*)(W + 91226112);           // [128][2048] f32
    float*          part   = (float*)W;                        // [8][128][2048] f32, aliases pre (dead then)

    // zero hbf2 (t=0 reads buf0 = h(0)=0) and the padded barrier counters (every replay)
    hipMemsetAsync(W + 85983232, 0, 524288 + 2048, stream);

    // GRU input projection: pre[d][b*80+t][1536] = videos @ Wih_d^T + bih_d (bf16 out)
    gemm_mfma<1, 1, 1><<<dim3(24, 80, 1), 256, 0, stream>>>(
        videos, 0l, 10240, 0l, 2048,
        Wih_f, Wih_b, 1536, 1536, 2048l, 0l,
        bih_f, bih_b, 1,
        pre, 15728640l, 1536l, 2048, 0l);

    // Fused persistent GRU scan: one cooperative launch, fence-free exchange.
    {
        void* args[] = { (void*)&pre, (void*)&hbf2, (void*)&Mp, (void*)&counters,
                         (void*)&Whh_f, (void*)&Whh_b, (void*)&bhh_f, (void*)&bhh_b };
        hipLaunchCooperativeKernel((const void*)k_gru_scan, dim3(128, 1, 1),
                                   dim3(256, 1, 1), args, 0, stream);
    }

    k_mask_mean<<<dim3(4, 128), 256, 0, stream>>>(Mp, mask, lengths, mean);

    // Convs: D[(b,tau),(i*512+kf)] = sum_d Mp[b,tau,d]*cw[kf,i,d] (bf16 D into pre region)
    for (int wi = 0; wi < 4; ++wi) {
        int ww = wi + 2;
        int N  = ww * 512;
        gemm_mfma<0, 1, 1><<<dim3(N / 128, 80, 1), 256, 0, stream>>>(
            Mp, 4096l, 80, 90112l, 1024,
            cw[wi], nullptr, 1 << 30, 512, (long)(ww * 1024), 1024l,
            nullptr, nullptr, 0,
            pre, 0l, (long)N, 1024, 0l);
        k_conv_epi<<<dim3(2, 128), 256, 0, stream>>>(pre, cb[wi], con, ww, wi);
    }

    k_gather<<<2560, 256, 0, stream>>>(mean, con, vorigin, fin);

    // map: split-K=8 MFMA GEMM -> f32 partials (alias pre), then reduce + bias.
    gemm_mfma<0, 1, 0><<<dim3(16, 1, 8), 256, 0, stream>>>(
        fin, 0l, 128, 0l, 5120,
        map_W, nullptr, 1 << 30, 2048, 5120l, 0l,
        nullptr, nullptr, 0,
        part, 0l, 2048l, 640, 262144l);
    k_map_reduce<<<1024, 256, 0, stream>>>(part, map_b, feat);

    k_bn_norm<<<128, 256, 0, stream>>>(feat, gamma, beta, (float*)d_out);
}

// Round 5
// 1696.105 us; speedup vs baseline: 1.4429x; 1.0306x over previous
//
#include <hip/hip_runtime.h>
#include <hip/hip_bf16.h>

// Video_multilevel_encoding — round 10: REVERT scan to round-7 (passed, 483 µs) and
// attack the GEMM staging bottleneck instead.
// Round-8/9 post-mortem: both failed with BIT-IDENTICAL absmax (7.476807e-02) across
// different coherence scopes -> deterministic logic bug in the 4-chunk pipeline, NOT a
// visibility race; two rounds were spent fixing the wrong layer. Scan below is the
// round-7 kernel verbatim (intra-XCD groups, fence-free relaxed agent atomics).
// This round's change: GEMM counters showed VALUBusy 49% vs MfmaUtil 17.8% — f32->bf16
// B-operand staging (stage8_f32) dominates, re-converting the same weights once per
// M-block (80x). Now weights are converted ONCE by k_f2b into time-multiplexed ws slots:
//   wih_bf  (12.6MB) -> Mp region (dead until scan)        [input-proj B]
//   cwbf    (<=5.2MB) -> pre tail @57.6MB (D uses <=52.4MB) [conv B, per-w]
//   mapw_bf (21MB)   -> pre+8.4MB (after part alias)        [map B]
// and all GEMMs use the pure-bf16 gld16 path for B.

#define T_SEQ 80

typedef __attribute__((ext_vector_type(8))) short short8;
typedef __attribute__((ext_vector_type(4))) float floatx4;

__device__ __forceinline__ float bf2f(unsigned short s) {
    union { unsigned int u; float f; } c; c.u = ((unsigned int)s) << 16; return c.f;
}
__device__ __forceinline__ unsigned short f2bf(float f) {
    union { float f; unsigned int u; } c; c.f = f;
    unsigned int u = c.u;
    u += 0x7fffu + ((u >> 16) & 1u);   // RNE
    return (unsigned short)(u >> 16);
}
// async global->LDS, 16B/lane; LDS dest wave-uniform base (HW scatters lane*16)
__device__ __forceinline__ void gld16(const unsigned short* g, unsigned short* lds_uniform) {
    __builtin_amdgcn_global_load_lds(
        (const __attribute__((address_space(1))) void*)g,
        (__attribute__((address_space(3))) void*)lds_uniform, 16, 0, 0);
}
// f32 source -> 8 bf16 into LDS (per-lane scatter via ds_write_b128)
__device__ __forceinline__ void stage8_f32(const float* __restrict__ src, unsigned short* __restrict__ dst) {
    float4 a = *(const float4*)src;
    float4 b = *(const float4*)(src + 4);
    short8 v;
    v[0] = (short)f2bf(a.x); v[1] = (short)f2bf(a.y); v[2] = (short)f2bf(a.z); v[3] = (short)f2bf(a.w);
    v[4] = (short)f2bf(b.x); v[5] = (short)f2bf(b.y); v[6] = (short)f2bf(b.z); v[7] = (short)f2bf(b.w);
    *(short8*)dst = v;
}

// f32 -> bf16 bulk convert, 8 elems/thread (RNE, same values stage8_f32 produced)
__global__ __launch_bounds__(256) void k_f2b(
    const float* __restrict__ src, unsigned short* __restrict__ dst, int n8)
{
    int e = blockIdx.x * 256 + threadIdx.x;
    if (e >= n8) return;
    float4 a = ((const float4*)src)[e * 2];
    float4 b = ((const float4*)src)[e * 2 + 1];
    short8 v;
    v[0] = (short)f2bf(a.x); v[1] = (short)f2bf(a.y); v[2] = (short)f2bf(a.z); v[3] = (short)f2bf(a.w);
    v[4] = (short)f2bf(b.x); v[5] = (short)f2bf(b.y); v[6] = (short)f2bf(b.z); v[7] = (short)f2bf(b.w);
    *(short8*)(dst + e * 8) = v;
}

// ---------------------------------------------------------------------------
// MFMA bf16 NT-GEMM, dual-mode staging. C[m,n] = sum_k A[m,k]*B[n,k] (+bias[n]).
// ---------------------------------------------------------------------------
template<int AF32, int BF32, int OUTBF>
__global__ __launch_bounds__(256) void gemm_mfma(
    const void* __restrict__ Av, long a_base, int a_rpb, long a_bstride, int a_rstride,
    const void* __restrict__ B1v, const void* __restrict__ B2v,
    int n_split, int b_mod, long b_sa, long b_sb,
    const float* __restrict__ bias1, const float* __restrict__ bias2, int has_bias,
    void* __restrict__ Cout, long out_dsplit, long ldc,
    int kchunk, long zout)
{
    __shared__ __align__(16) unsigned short As[128 * 32];
    __shared__ __align__(16) unsigned short Bs[128 * 32];
    const int tid = threadIdx.x, wave = tid >> 6, lane = tid & 63;
    const int m0 = blockIdx.y * 128, n0 = blockIdx.x * 128;
    const long kbeg = (long)blockIdx.z * kchunk;

    const int c0 = wave * 64 + lane, c1 = 256 + c0;
    const int rA0 = c0 >> 2, pA0 = c0 & 3, rA1 = c1 >> 2, pA1 = c1 & 3;
    const int am0 = m0 + rA0, am1 = m0 + rA1;
    const long aoff0 = a_base + (long)(am0 / a_rpb) * a_bstride + (long)(am0 % a_rpb) * a_rstride + pA0 * 8 + kbeg;
    const long aoff1 = a_base + (long)(am1 / a_rpb) * a_bstride + (long)(am1 % a_rpb) * a_rstride + pA1 * 8 + kbeg;

    const int bn0 = n0 + rA0, bn1 = n0 + rA1;
    const int bd0 = (bn0 >= n_split), bd1 = (bn1 >= n_split);
    const int br0 = bn0 - (bd0 ? n_split : 0), br1 = bn1 - (bd1 ? n_split : 0);
    const long boff0 = (long)(br0 % b_mod) * b_sa + (long)(br0 / b_mod) * b_sb + pA0 * 8 + kbeg;
    const long boff1 = (long)(br1 % b_mod) * b_sa + (long)(br1 / b_mod) * b_sb + pA1 * 8 + kbeg;
    const void* Bp0 = bd0 ? B2v : B1v;
    const void* Bp1 = bd1 ? B2v : B1v;

    const int frow = lane & 15, fq = lane >> 4;
    const int wm = (wave >> 1) * 64, wn = (wave & 1) * 64;

    floatx4 acc[4][4];
    #pragma unroll
    for (int i = 0; i < 4; ++i)
        #pragma unroll
        for (int j = 0; j < 4; ++j) acc[i][j] = (floatx4)0.f;

    for (int k0 = 0; k0 < kchunk; k0 += 32) {
        if (AF32) {
            stage8_f32((const float*)Av + aoff0 + k0, As + c0 * 8);
            stage8_f32((const float*)Av + aoff1 + k0, As + c1 * 8);
        } else {
            gld16((const unsigned short*)Av + aoff0 + k0, As + (wave * 64) * 8);
            gld16((const unsigned short*)Av + aoff1 + k0, As + (256 + wave * 64) * 8);
        }
        if (BF32) {
            stage8_f32((const float*)Bp0 + boff0 + k0, Bs + c0 * 8);
            stage8_f32((const float*)Bp1 + boff1 + k0, Bs + c1 * 8);
        } else {
            gld16((const unsigned short*)Bp0 + boff0 + k0, Bs + (wave * 64) * 8);
            gld16((const unsigned short*)Bp1 + boff1 + k0, Bs + (256 + wave * 64) * 8);
        }
        __syncthreads();
        short8 af[4], bf[4];
        #pragma unroll
        for (int i = 0; i < 4; ++i) {
            af[i] = *(const short8*)&As[(wm + i * 16 + frow) * 32 + fq * 8];
            bf[i] = *(const short8*)&Bs[(wn + i * 16 + frow) * 32 + fq * 8];
        }
        #pragma unroll
        for (int mi = 0; mi < 4; ++mi)
            #pragma unroll
            for (int ni = 0; ni < 4; ++ni)
                acc[mi][ni] = __builtin_amdgcn_mfma_f32_16x16x32_bf16(af[mi], bf[ni], acc[mi][ni], 0, 0, 0);
        __syncthreads();
    }

    const long zoff = (long)blockIdx.z * zout;
    #pragma unroll
    for (int mi = 0; mi < 4; ++mi) {
        #pragma unroll
        for (int ni = 0; ni < 4; ++ni) {
            const int na = n0 + wn + ni * 16 + frow;
            const int dd = (na >= n_split);
            const int g  = na - (dd ? n_split : 0);
            float bv = has_bias ? (dd ? bias2 : bias1)[g] : 0.f;
            #pragma unroll
            for (int r = 0; r < 4; ++r) {
                const long gm = m0 + wm + mi * 16 + fq * 4 + r;
                const float v = acc[mi][ni][r] + bv;
                const long cidx = zoff + (dd ? out_dsplit : 0) + gm * ldc + g;
                if (OUTBF) ((unsigned short*)Cout)[cidx] = f2bf(v);
                else       ((float*)Cout)[cidx] = v;
            }
        }
    }
}

// ---------------------------------------------------------------------------
// Persistent fused GRU scan — ROUND-7 KERNEL VERBATIM (passed, 483 µs).
// Grid (128,1,1) x 256 thr. gid = bx&7 (group on one XCD), cc = bx>>3.
// ---------------------------------------------------------------------------
__global__ __launch_bounds__(256) void k_gru_scan(
    const unsigned short* __restrict__ pre,      // [2][10240][1536] bf16
    unsigned short* __restrict__ hbf2,           // [2 buf][2 dir][128][512] bf16
    unsigned short* __restrict__ Mp,             // [128][88][1024] bf16
    unsigned int* __restrict__ counters,         // [8][64] (256B-padded), zeroed
    const float* __restrict__ Whh_f, const float* __restrict__ Whh_b,
    const float* __restrict__ bhh_f, const float* __restrict__ bhh_b)
{
    __shared__ __align__(16) unsigned short Wlds[96][520];  // 99,840 B

    const int tid = threadIdx.x, wave = tid >> 6, lane = tid & 63;
    const int bx = blockIdx.x;
    const int cc = bx >> 3, gid = bx & 7;        // group gid -> one XCD (perf heuristic)
    const int d = gid >> 2, bb = gid & 3;
    const int c0 = cc * 32;
    const float* WhhD = d ? Whh_b : Whh_f;
    const float* bhhD = d ? bhh_b : bhh_f;

    // prologue: Whh slice (3 gates x 32 cols x 512 K) -> LDS bf16 (RNE)
    for (int e = tid; e < 6144; e += 256) {
        const int r = e >> 6, p = e & 63;        // r = g*32 + jp
        const int g = r >> 5, jp = r & 31;
        stage8_f32(WhhD + ((long)(g * 512 + c0 + jp)) * 512 + p * 8, &Wlds[r][p * 8]);
    }

    const int frow = lane & 15, fq = lane >> 4;
    const int wr = wave & 1, wc = wave >> 1;
    const int myc = c0 + wc * 16 + frow;             // owned h col in [0,512)
    const int rbase = wr * 16 + fq * 4;
    const long arow = (long)(bb * 32 + wr * 16 + frow) * 512 + fq * 8;
    const int even = ((frow & 1) == 0);
    const int cpair = myc & ~1;

    float bres[3];
    #pragma unroll
    for (int g = 0; g < 3; ++g) bres[g] = bhhD[g * 512 + myc];

    float hreg[4] = {0.f, 0.f, 0.f, 0.f};           // h f32 carried in registers
    unsigned int* cnt = counters + gid * 64;

    // pre for t=0
    float pv[3][4];
    {
        const int ti0 = d ? (T_SEQ - 1) : 0;
        #pragma unroll
        for (int q = 0; q < 4; ++q) {
            const unsigned short* pb = pre + (long)d * 15728640 + ((long)(bb * 32 + rbase + q) * T_SEQ + ti0) * 1536 + myc;
            pv[0][q] = bf2f(pb[0]); pv[1][q] = bf2f(pb[512]); pv[2][q] = bf2f(pb[1024]);
        }
    }

    __syncthreads();   // Wlds ready

    #pragma unroll 1
    for (int t = 0; t < T_SEQ; ++t) {
        const int ti = d ? (T_SEQ - 1 - t) : t;
        const unsigned short* hread = hbf2 + ((t & 1) * 2 + d) * 65536;

        // A fragments: 16 rows x K=512 via relaxed agent atomic u64 (coherent, no fence)
        short8 af[16];
        #pragma unroll
        for (int kk = 0; kk < 16; ++kk) {
            union { unsigned long long u[2]; short8 s; } cv;
            unsigned long long* p = (unsigned long long*)(hread + arow + kk * 32);
            cv.u[0] = __hip_atomic_load(p,     __ATOMIC_RELAXED, __HIP_MEMORY_SCOPE_AGENT);
            cv.u[1] = __hip_atomic_load(p + 1, __ATOMIC_RELAXED, __HIP_MEMORY_SCOPE_AGENT);
            af[kk] = cv.s;
        }

        floatx4 acc[3] = {(floatx4)0.f, (floatx4)0.f, (floatx4)0.f};
        #pragma unroll
        for (int kk = 0; kk < 16; ++kk) {
            #pragma unroll
            for (int g = 0; g < 3; ++g) {
                const short8 bfr = *(const short8*)&Wlds[g * 32 + wc * 16 + frow][kk * 32 + fq * 8];
                acc[g] = __builtin_amdgcn_mfma_f32_16x16x32_bf16(af[kk], bfr, acc[g], 0, 0, 0);
            }
        }

        // gate update, fully in registers
        unsigned long long hv4 = 0ull;               // q-th bf16 at bits [16q,16q+16)
        #pragma unroll
        for (int q = 0; q < 4; ++q) {
            const float gr = acc[0][q] + bres[0];
            const float gz = acc[1][q] + bres[1];
            const float gn = acc[2][q] + bres[2];
            const float rr = 1.f / (1.f + expf(-(pv[0][q] + gr)));
            const float zz = 1.f / (1.f + expf(-(pv[1][q] + gz)));
            const float nn = tanhf(pv[2][q] + rr * gn);
            const float hnew = (1.f - zz) * nn + zz * hreg[q];
            hreg[q] = hnew;
            hv4 |= (unsigned long long)f2bf(hnew) << (16 * q);
        }

        // pair adjacent cols (lanes frow 2i/2i+1) -> packed u32 stores, 2 rows each
        const unsigned long long prt = __shfl_xor(hv4, 1, 64);
        unsigned short* hw = hbf2 + (((t + 1) & 1) * 2 + d) * 65536;
        #pragma unroll
        for (int s = 0; s < 2; ++s) {
            const int q = even ? s : (2 + s);
            const unsigned int lo = (unsigned int)((even ? hv4 : prt) >> (16 * q)) & 0xffffu;
            const unsigned int hi = (unsigned int)((even ? prt : hv4) >> (16 * q)) & 0xffffu;
            const unsigned int pk = lo | (hi << 16);
            const long rowg = bb * 32 + rbase + q;
            __hip_atomic_store((unsigned int*)(hw + rowg * 512 + cpair), pk,
                               __ATOMIC_RELAXED, __HIP_MEMORY_SCOPE_AGENT);
            *(unsigned int*)(Mp + rowg * 90112 + (long)(4 + ti) * 1024 + d * 512 + cpair) = pk;
        }

        // pre prefetch for t+1 (h-independent) before the barrier
        if (t + 1 < T_SEQ) {
            const int tn = d ? (T_SEQ - 2 - t) : (t + 1);
            #pragma unroll
            for (int q = 0; q < 4; ++q) {
                const unsigned short* pb = pre + (long)d * 15728640 + ((long)(bb * 32 + rbase + q) * T_SEQ + tn) * 1536 + myc;
                pv[0][q] = bf2f(pb[0]); pv[1][q] = bf2f(pb[512]); pv[2][q] = bf2f(pb[1024]);
            }
        }

        // group barrier: syncthreads drains vmcnt(0) -> h stores acked at coherence
        // point before the relaxed add; peers observing counter observe h.
        __syncthreads();
        if (tid == 0) {
            __hip_atomic_fetch_add(cnt, 1u, __ATOMIC_RELAXED, __HIP_MEMORY_SCOPE_AGENT);
            const unsigned int target = (unsigned int)(t + 1) * 16u;
            while (__hip_atomic_load(cnt, __ATOMIC_RELAXED, __HIP_MEMORY_SCOPE_AGENT) < target)
                __builtin_amdgcn_s_sleep(1);
        }
        __syncthreads();
    }
}

// Mask Mp in place (bf16 * {0,1} lossless) and mean over valid steps. mask is f32.
__global__ __launch_bounds__(256) void k_mask_mean(
    unsigned short* __restrict__ Mp, const float* __restrict__ mask,
    const int* __restrict__ lengths, float* __restrict__ mean)
{
    const int b = blockIdx.y;
    const int c = blockIdx.x * 256 + threadIdx.x;
    float acc = 0.f;
    unsigned short* base = Mp + (long)b * 90112 + 4096 + c;
    for (int t = 0; t < T_SEQ; ++t) {
        float m = mask[b * T_SEQ + t];
        float v = bf2f(base[t * 1024]) * m;
        base[t * 1024] = f2bf(v);
        acc += v;
    }
    mean[b * 1024 + c] = acc / (float)lengths[b];
}

// Conv epilogue over bf16 D: c[b,kf,t] = sum_i D[b, t-w+1+i, i*512+kf]; relu(bias+max_t).
__global__ __launch_bounds__(256) void k_conv_epi(
    const unsigned short* __restrict__ D, const float* __restrict__ cb,
    float* __restrict__ con, int w, int widx)
{
    const int b  = blockIdx.y;
    const int kf = blockIdx.x * 256 + threadIdx.x;
    const int N  = w * 512;
    const unsigned short* Db = D + (long)b * T_SEQ * N;
    float mx = -1e30f;
    for (int t = 0; t < T_SEQ + w - 1; ++t) {
        float s = 0.f;
        for (int i = 0; i < w; ++i) {
            int tau = t - w + 1 + i;
            if (tau >= 0 && tau < T_SEQ) s += bf2f(Db[(long)tau * N + i * 512 + kf]);
        }
        mx = fmaxf(mx, s);
    }
    con[b * 2048 + widx * 512 + kf] = fmaxf(0.f, mx + cb[kf]);
}

// Assemble map input (bf16 for MFMA map GEMM): [mean | con | videos_origin(f32)].
__global__ __launch_bounds__(256) void k_gather(
    const float* __restrict__ mean, const float* __restrict__ con,
    const float* __restrict__ vo, unsigned short* __restrict__ fin)
{
    int e = blockIdx.x * 256 + threadIdx.x;     // < 655360
    int b = e / 5120, k = e - b * 5120;
    float v;
    if (k < 1024)      v = mean[b * 1024 + k];
    else if (k < 3072) v = con[b * 2048 + (k - 1024)];
    else               v = vo[b * 2048 + (k - 3072)];
    fin[e] = f2bf(v);
}

// Reduce split-K partials + bias (f32) -> feat.
__global__ __launch_bounds__(256) void k_map_reduce(
    const float* __restrict__ part, const float* __restrict__ map_b,
    float* __restrict__ feat)
{
    int e = blockIdx.x * 256 + threadIdx.x;     // < 262144
    float s = map_b[e & 2047];
    #pragma unroll
    for (int z = 0; z < 8; ++z) s += part[(long)z * 262144 + e];
    feat[e] = s;
}

// BN (eval: /sqrt(1+eps)*gamma+beta) + row L2-normalize -> f32 out.
__global__ __launch_bounds__(256) void k_bn_norm(
    const float* __restrict__ feat, const float* __restrict__ gamma,
    const float* __restrict__ beta, float* __restrict__ out)
{
    const int b = blockIdx.x, tid = threadIdx.x;
    const float inv_c = 1.f / sqrtf(1.f + 1e-5f);
    float y[8]; float ss = 0.f;
    #pragma unroll
    for (int u = 0; u < 8; ++u) {
        int o = u * 256 + tid;
        float v = feat[b * 2048 + o] * inv_c * gamma[o] + beta[o];
        y[u] = v; ss += v * v;
    }
    #pragma unroll
    for (int off = 32; off >= 1; off >>= 1) ss += __shfl_down(ss, off, 64);
    __shared__ float rs[4];
    if ((tid & 63) == 0) rs[tid >> 6] = ss;
    __syncthreads();
    float rn = 1.f / sqrtf(rs[0] + rs[1] + rs[2] + rs[3]);
    #pragma unroll
    for (int u = 0; u < 8; ++u) {
        int o = u * 256 + tid;
        out[b * 2048 + o] = y[u] * rn;
    }
}

extern "C" void kernel_launch(void* const* d_in, const int* in_sizes, int n_in,
                              void* d_out, int out_size, void* d_ws, size_t ws_size,
                              hipStream_t stream)
{
    const float* videos  = (const float*)d_in[0];
    const float* vorigin = (const float*)d_in[1];
    const int*   lengths = (const int*)d_in[2];
    const float* mask    = (const float*)d_in[3];
    // d_in[4] gru_text_out: unused by the reference
    const float* Wih_f = (const float*)d_in[5];
    const float* Whh_f = (const float*)d_in[6];
    const float* bih_f = (const float*)d_in[7];
    const float* bhh_f = (const float*)d_in[8];
    const float* Wih_b = (const float*)d_in[9];
    const float* Whh_b = (const float*)d_in[10];
    const float* bih_b = (const float*)d_in[11];
    const float* bhh_b = (const float*)d_in[12];
    // d_in[13..16] attention: dead (softmax over size-1 axis == 1)
    const float* cw[4] = { (const float*)d_in[17], (const float*)d_in[19],
                           (const float*)d_in[21], (const float*)d_in[23] };
    const float* cb[4] = { (const float*)d_in[18], (const float*)d_in[20],
                           (const float*)d_in[22], (const float*)d_in[24] };
    const float* map_W = (const float*)d_in[25];
    const float* map_b = (const float*)d_in[26];
    const float* gamma = (const float*)d_in[27];
    const float* beta  = (const float*)d_in[28];

    // --- workspace layout (bytes) ---
    unsigned char* W = (unsigned char*)d_ws;
    unsigned short* pre    = (unsigned short*)W;               // [2][10240][1536] bf16 (GRU pre; conv D + part + mapw_bf alias later)
    unsigned short* Mp     = (unsigned short*)(W + 62914560);  // [128][88][1024] bf16
    unsigned short* hbf2   = (unsigned short*)(W + 85983232);  // [2 buf][2 dir][128][512] bf16
    unsigned int*   counters = (unsigned int*)(W + 86507520);  // [8][64] padded barrier counters (2048 B)
    float*          mean   = (float*)(W + 88342528);           // [128][1024] f32
    float*          con    = (float*)(W + 88866816);           // [128][2048] f32
    unsigned short* fin    = (unsigned short*)(W + 89915392);  // [128][5120] bf16
    float*          feat   = (float*)(W + 91226112);           // [128][2048] f32
    float*          part   = (float*)W;                        // [8][128][2048] f32, aliases pre (dead then)
    // time-multiplexed bf16 weight slots:
    unsigned short* wih_bf  = (unsigned short*)(W + 62914560); // 12.6MB in Mp region (dead pre-scan)
    unsigned short* cwbf    = (unsigned short*)(W + 57671680); // <=5.2MB pre-tail (conv D <= 52.4MB)
    unsigned short* mapw_bf = (unsigned short*)(W + 8388608);  // 21MB after part (pre dead post-conv)

    // zero hbf2 (t=0 reads buf0 = h(0)=0) and the padded barrier counters (every replay)
    hipMemsetAsync(W + 85983232, 0, 524288 + 2048, stream);

    // Wih (2 dirs, [1536][2048] f32 each) -> wih_bf bf16, contiguous [2][1536][2048]
    k_f2b<<<3072, 256, 0, stream>>>(Wih_f, wih_bf, 393216);
    k_f2b<<<3072, 256, 0, stream>>>(Wih_b, wih_bf + 3145728, 393216);

    // GRU input projection: pre[d][b*80+t][1536] = videos @ Wih_d^T + bih_d (bf16 out)
    // A = videos f32 (staged), B = wih_bf bf16 (gld16).
    gemm_mfma<1, 0, 1><<<dim3(24, 80, 1), 256, 0, stream>>>(
        videos, 0l, 10240, 0l, 2048,
        wih_bf, wih_bf + 3145728, 1536, 1536, 2048l, 0l,
        bih_f, bih_b, 1,
        pre, 15728640l, 1536l, 2048, 0l);

    // Fused persistent GRU scan (round-7 kernel): one cooperative launch.
    {
        const unsigned short* prec = pre;
        void* args[] = { (void*)&prec, (void*)&hbf2, (void*)&Mp, (void*)&counters,
                         (void*)&Whh_f, (void*)&Whh_b, (void*)&bhh_f, (void*)&bhh_b };
        hipLaunchCooperativeKernel((const void*)k_gru_scan, dim3(128, 1, 1),
                                   dim3(256, 1, 1), args, 0, stream);
    }

    k_mask_mean<<<dim3(4, 128), 256, 0, stream>>>(Mp, mask, lengths, mean);

    // Convs: D[(b,tau),(i*512+kf)] = sum_d Mp[b,tau,d]*cw[kf,i,d] (bf16 D into pre region)
    // B weights converted to bf16 per-w into cwbf (pure gld16 GEMM).
    for (int wi = 0; wi < 4; ++wi) {
        int ww = wi + 2;
        int N  = ww * 512;
        k_f2b<<<ww * 256, 256, 0, stream>>>(cw[wi], cwbf, ww * 65536);
        gemm_mfma<0, 0, 1><<<dim3(N / 128, 80, 1), 256, 0, stream>>>(
            Mp, 4096l, 80, 90112l, 1024,
            cwbf, nullptr, 1 << 30, 512, (long)(ww * 1024), 1024l,
            nullptr, nullptr, 0,
            pre, 0l, (long)N, 1024, 0l);
        k_conv_epi<<<dim3(2, 128), 256, 0, stream>>>(pre, cb[wi], con, ww, wi);
    }

    k_gather<<<2560, 256, 0, stream>>>(mean, con, vorigin, fin);

    // map: convert map_W -> bf16 (pre region beyond part is dead), split-K=8 GEMM.
    k_f2b<<<5120, 256, 0, stream>>>(map_W, mapw_bf, 1310720);
    gemm_mfma<0, 0, 0><<<dim3(16, 1, 8), 256, 0, stream>>>(
        fin, 0l, 128, 0l, 5120,
        mapw_bf, nullptr, 1 << 30, 2048, 5120l, 0l,
        nullptr, nullptr, 0,
        part, 0l, 2048l, 640, 262144l);
    k_map_reduce<<<1024, 256, 0, stream>>>(part, map_b, feat);

    k_bn_norm<<<128, 256, 0, stream>>>(feat, gamma, beta, (float*)d_out);
}

// Round 6
// 1616.111 us; speedup vs baseline: 1.5143x; 1.0495x over previous
//
#include <hip/hip_runtime.h>
#include <hip/hip_bf16.h>

// Video_multilevel_encoding — round 11: three proven-bottleneck, low-blast-radius fixes.
// r10 post-mortem: B-bf16 pre-conversion gained only 52 µs -> GEMMs not B-staging-bound.
// Remaining per counters: (1) A-side f32->bf16 staging VALU (manual f2bf ~5 ops/elem;
// VALUBusy 49%) -> v_cvt_pk_bf16_f32 (2 elems/instr, RNE, bit-identical); (2) A-panel
// XCD locality: grid (24,80) puts the 24 sharers of an A row-block on all 8 XCDs ->
// linear grid with by=id%80 (stride-80 ids = same XCD under id%8 round-robin), A-tile
// lives in ONE L2; (3) scan: per-step __syncthreads drains the 12 scattered HBM pre
// prefetch loads inside the barrier -> move prefetch between tid0-add and tid0-spin so
// the HBM latency overlaps the wait-for-slowest-peer window. Scan protocol/data path
// UNTOUCHED (r7 verbatim otherwise; r8/r9 lesson).

#define T_SEQ 80

typedef __attribute__((ext_vector_type(8))) short short8;
typedef __attribute__((ext_vector_type(4))) float floatx4;

__device__ __forceinline__ float bf2f(unsigned short s) {
    union { unsigned int u; float f; } c; c.u = ((unsigned int)s) << 16; return c.f;
}
__device__ __forceinline__ unsigned short f2bf(float f) {
    union { float f; unsigned int u; } c; c.f = f;
    unsigned int u = c.u;
    u += 0x7fffu + ((u >> 16) & 1u);   // RNE
    return (unsigned short)(u >> 16);
}
// packed f32x2 -> bf16x2 (RNE, HW) — bit-identical to f2bf for finite inputs
__device__ __forceinline__ unsigned int cvtpk(float lo, float hi) {
    unsigned int r;
    asm("v_cvt_pk_bf16_f32 %0, %1, %2" : "=v"(r) : "v"(lo), "v"(hi));
    return r;
}
// async global->LDS, 16B/lane; LDS dest wave-uniform base (HW scatters lane*16)
__device__ __forceinline__ void gld16(const unsigned short* g, unsigned short* lds_uniform) {
    __builtin_amdgcn_global_load_lds(
        (const __attribute__((address_space(1))) void*)g,
        (__attribute__((address_space(3))) void*)lds_uniform, 16, 0, 0);
}
// f32 source -> 8 bf16 into LDS (per-lane scatter via ds_write_b128), cvt_pk path
__device__ __forceinline__ void stage8_f32(const float* __restrict__ src, unsigned short* __restrict__ dst) {
    float4 a = *(const float4*)src;
    float4 b = *(const float4*)(src + 4);
    union { unsigned int u[4]; short8 s; } p;
    p.u[0] = cvtpk(a.x, a.y); p.u[1] = cvtpk(a.z, a.w);
    p.u[2] = cvtpk(b.x, b.y); p.u[3] = cvtpk(b.z, b.w);
    *(short8*)dst = p.s;
}

// f32 -> bf16 bulk convert, 8 elems/thread
__global__ __launch_bounds__(256) void k_f2b(
    const float* __restrict__ src, unsigned short* __restrict__ dst, int n8)
{
    int e = blockIdx.x * 256 + threadIdx.x;
    if (e >= n8) return;
    float4 a = ((const float4*)src)[e * 2];
    float4 b = ((const float4*)src)[e * 2 + 1];
    union { unsigned int u[4]; short8 s; } p;
    p.u[0] = cvtpk(a.x, a.y); p.u[1] = cvtpk(a.z, a.w);
    p.u[2] = cvtpk(b.x, b.y); p.u[3] = cvtpk(b.z, b.w);
    *(short8*)(dst + e * 8) = p.s;
}

// ---------------------------------------------------------------------------
// MFMA bf16 NT-GEMM, dual-mode staging. C[m,n] = sum_k A[m,k]*B[n,k] (+bias[n]).
// m_rr != 0: linear grid, by = blockIdx.x % m_rr, bx = blockIdx.x / m_rr
// (same-by blocks land on one XCD under id%8 round-robin -> A-panel L2 locality).
// ---------------------------------------------------------------------------
template<int AF32, int BF32, int OUTBF>
__global__ __launch_bounds__(256) void gemm_mfma(
    const void* __restrict__ Av, long a_base, int a_rpb, long a_bstride, int a_rstride,
    const void* __restrict__ B1v, const void* __restrict__ B2v,
    int n_split, int b_mod, long b_sa, long b_sb,
    const float* __restrict__ bias1, const float* __restrict__ bias2, int has_bias,
    void* __restrict__ Cout, long out_dsplit, long ldc,
    int kchunk, long zout, int m_rr)
{
    __shared__ __align__(16) unsigned short As[128 * 32];
    __shared__ __align__(16) unsigned short Bs[128 * 32];
    const int tid = threadIdx.x, wave = tid >> 6, lane = tid & 63;
    int bxl, byl;
    if (m_rr) { byl = (int)blockIdx.x % m_rr; bxl = (int)blockIdx.x / m_rr; }
    else      { bxl = blockIdx.x; byl = blockIdx.y; }
    const int m0 = byl * 128, n0 = bxl * 128;
    const long kbeg = (long)blockIdx.z * kchunk;

    const int c0 = wave * 64 + lane, c1 = 256 + c0;
    const int rA0 = c0 >> 2, pA0 = c0 & 3, rA1 = c1 >> 2, pA1 = c1 & 3;
    const int am0 = m0 + rA0, am1 = m0 + rA1;
    const long aoff0 = a_base + (long)(am0 / a_rpb) * a_bstride + (long)(am0 % a_rpb) * a_rstride + pA0 * 8 + kbeg;
    const long aoff1 = a_base + (long)(am1 / a_rpb) * a_bstride + (long)(am1 % a_rpb) * a_rstride + pA1 * 8 + kbeg;

    const int bn0 = n0 + rA0, bn1 = n0 + rA1;
    const int bd0 = (bn0 >= n_split), bd1 = (bn1 >= n_split);
    const int br0 = bn0 - (bd0 ? n_split : 0), br1 = bn1 - (bd1 ? n_split : 0);
    const long boff0 = (long)(br0 % b_mod) * b_sa + (long)(br0 / b_mod) * b_sb + pA0 * 8 + kbeg;
    const long boff1 = (long)(br1 % b_mod) * b_sa + (long)(br1 / b_mod) * b_sb + pA1 * 8 + kbeg;
    const void* Bp0 = bd0 ? B2v : B1v;
    const void* Bp1 = bd1 ? B2v : B1v;

    const int frow = lane & 15, fq = lane >> 4;
    const int wm = (wave >> 1) * 64, wn = (wave & 1) * 64;

    floatx4 acc[4][4];
    #pragma unroll
    for (int i = 0; i < 4; ++i)
        #pragma unroll
        for (int j = 0; j < 4; ++j) acc[i][j] = (floatx4)0.f;

    for (int k0 = 0; k0 < kchunk; k0 += 32) {
        if (AF32) {
            stage8_f32((const float*)Av + aoff0 + k0, As + c0 * 8);
            stage8_f32((const float*)Av + aoff1 + k0, As + c1 * 8);
        } else {
            gld16((const unsigned short*)Av + aoff0 + k0, As + (wave * 64) * 8);
            gld16((const unsigned short*)Av + aoff1 + k0, As + (256 + wave * 64) * 8);
        }
        if (BF32) {
            stage8_f32((const float*)Bp0 + boff0 + k0, Bs + c0 * 8);
            stage8_f32((const float*)Bp1 + boff1 + k0, Bs + c1 * 8);
        } else {
            gld16((const unsigned short*)Bp0 + boff0 + k0, Bs + (wave * 64) * 8);
            gld16((const unsigned short*)Bp1 + boff1 + k0, Bs + (256 + wave * 64) * 8);
        }
        __syncthreads();
        short8 af[4], bf[4];
        #pragma unroll
        for (int i = 0; i < 4; ++i) {
            af[i] = *(const short8*)&As[(wm + i * 16 + frow) * 32 + fq * 8];
            bf[i] = *(const short8*)&Bs[(wn + i * 16 + frow) * 32 + fq * 8];
        }
        #pragma unroll
        for (int mi = 0; mi < 4; ++mi)
            #pragma unroll
            for (int ni = 0; ni < 4; ++ni)
                acc[mi][ni] = __builtin_amdgcn_mfma_f32_16x16x32_bf16(af[mi], bf[ni], acc[mi][ni], 0, 0, 0);
        __syncthreads();
    }

    const long zoff = (long)blockIdx.z * zout;
    #pragma unroll
    for (int mi = 0; mi < 4; ++mi) {
        #pragma unroll
        for (int ni = 0; ni < 4; ++ni) {
            const int na = n0 + wn + ni * 16 + frow;
            const int dd = (na >= n_split);
            const int g  = na - (dd ? n_split : 0);
            float bv = has_bias ? (dd ? bias2 : bias1)[g] : 0.f;
            #pragma unroll
            for (int r = 0; r < 4; ++r) {
                const long gm = m0 + wm + mi * 16 + fq * 4 + r;
                const float v = acc[mi][ni][r] + bv;
                const long cidx = zoff + (dd ? out_dsplit : 0) + gm * ldc + g;
                if (OUTBF) ((unsigned short*)Cout)[cidx] = f2bf(v);
                else       ((float*)Cout)[cidx] = v;
            }
        }
    }
}

// ---------------------------------------------------------------------------
// Persistent fused GRU scan — round-7 protocol (passed), only change: pre-prefetch
// moved between the tid0 arrive (add) and the tid0 spin, so its HBM latency overlaps
// the wait-for-slowest-peer window instead of being drained serially at sync1.
// Grid (128,1,1) x 256 thr. gid = bx&7 (group on one XCD), cc = bx>>3.
// ---------------------------------------------------------------------------
__global__ __launch_bounds__(256) void k_gru_scan(
    const unsigned short* __restrict__ pre,      // [2][10240][1536] bf16
    unsigned short* __restrict__ hbf2,           // [2 buf][2 dir][128][512] bf16
    unsigned short* __restrict__ Mp,             // [128][88][1024] bf16
    unsigned int* __restrict__ counters,         // [8][64] (256B-padded), zeroed
    const float* __restrict__ Whh_f, const float* __restrict__ Whh_b,
    const float* __restrict__ bhh_f, const float* __restrict__ bhh_b)
{
    __shared__ __align__(16) unsigned short Wlds[96][520];  // 99,840 B

    const int tid = threadIdx.x, wave = tid >> 6, lane = tid & 63;
    const int bx = blockIdx.x;
    const int cc = bx >> 3, gid = bx & 7;        // group gid -> one XCD (perf heuristic)
    const int d = gid >> 2, bb = gid & 3;
    const int c0 = cc * 32;
    const float* WhhD = d ? Whh_b : Whh_f;
    const float* bhhD = d ? bhh_b : bhh_f;

    // prologue: Whh slice (3 gates x 32 cols x 512 K) -> LDS bf16 (RNE)
    for (int e = tid; e < 6144; e += 256) {
        const int r = e >> 6, p = e & 63;        // r = g*32 + jp
        const int g = r >> 5, jp = r & 31;
        stage8_f32(WhhD + ((long)(g * 512 + c0 + jp)) * 512 + p * 8, &Wlds[r][p * 8]);
    }

    const int frow = lane & 15, fq = lane >> 4;
    const int wr = wave & 1, wc = wave >> 1;
    const int myc = c0 + wc * 16 + frow;             // owned h col in [0,512)
    const int rbase = wr * 16 + fq * 4;
    const long arow = (long)(bb * 32 + wr * 16 + frow) * 512 + fq * 8;
    const int even = ((frow & 1) == 0);
    const int cpair = myc & ~1;

    float bres[3];
    #pragma unroll
    for (int g = 0; g < 3; ++g) bres[g] = bhhD[g * 512 + myc];

    float hreg[4] = {0.f, 0.f, 0.f, 0.f};           // h f32 carried in registers
    unsigned int* cnt = counters + gid * 64;

    // pre for t=0
    float pv[3][4];
    {
        const int ti0 = d ? (T_SEQ - 1) : 0;
        #pragma unroll
        for (int q = 0; q < 4; ++q) {
            const unsigned short* pb = pre + (long)d * 15728640 + ((long)(bb * 32 + rbase + q) * T_SEQ + ti0) * 1536 + myc;
            pv[0][q] = bf2f(pb[0]); pv[1][q] = bf2f(pb[512]); pv[2][q] = bf2f(pb[1024]);
        }
    }

    __syncthreads();   // Wlds ready

    #pragma unroll 1
    for (int t = 0; t < T_SEQ; ++t) {
        const int ti = d ? (T_SEQ - 1 - t) : t;
        const unsigned short* hread = hbf2 + ((t & 1) * 2 + d) * 65536;

        // A fragments: 16 rows x K=512 via relaxed agent atomic u64 (coherent, no fence)
        short8 af[16];
        #pragma unroll
        for (int kk = 0; kk < 16; ++kk) {
            union { unsigned long long u[2]; short8 s; } cv;
            unsigned long long* p = (unsigned long long*)(hread + arow + kk * 32);
            cv.u[0] = __hip_atomic_load(p,     __ATOMIC_RELAXED, __HIP_MEMORY_SCOPE_AGENT);
            cv.u[1] = __hip_atomic_load(p + 1, __ATOMIC_RELAXED, __HIP_MEMORY_SCOPE_AGENT);
            af[kk] = cv.s;
        }

        floatx4 acc[3] = {(floatx4)0.f, (floatx4)0.f, (floatx4)0.f};
        #pragma unroll
        for (int kk = 0; kk < 16; ++kk) {
            #pragma unroll
            for (int g = 0; g < 3; ++g) {
                const short8 bfr = *(const short8*)&Wlds[g * 32 + wc * 16 + frow][kk * 32 + fq * 8];
                acc[g] = __builtin_amdgcn_mfma_f32_16x16x32_bf16(af[kk], bfr, acc[g], 0, 0, 0);
            }
        }

        // gate update, fully in registers
        unsigned long long hv4 = 0ull;               // q-th bf16 at bits [16q,16q+16)
        #pragma unroll
        for (int q = 0; q < 4; ++q) {
            const float gr = acc[0][q] + bres[0];
            const float gz = acc[1][q] + bres[1];
            const float gn = acc[2][q] + bres[2];
            const float rr = 1.f / (1.f + expf(-(pv[0][q] + gr)));
            const float zz = 1.f / (1.f + expf(-(pv[1][q] + gz)));
            const float nn = tanhf(pv[2][q] + rr * gn);
            const float hnew = (1.f - zz) * nn + zz * hreg[q];
            hreg[q] = hnew;
            hv4 |= (unsigned long long)f2bf(hnew) << (16 * q);
        }

        // pair adjacent cols (lanes frow 2i/2i+1) -> packed u32 stores, 2 rows each
        const unsigned long long prt = __shfl_xor(hv4, 1, 64);
        unsigned short* hw = hbf2 + (((t + 1) & 1) * 2 + d) * 65536;
        #pragma unroll
        for (int s = 0; s < 2; ++s) {
            const int q = even ? s : (2 + s);
            const unsigned int lo = (unsigned int)((even ? hv4 : prt) >> (16 * q)) & 0xffffu;
            const unsigned int hi = (unsigned int)((even ? prt : hv4) >> (16 * q)) & 0xffffu;
            const unsigned int pk = lo | (hi << 16);
            const long rowg = bb * 32 + rbase + q;
            __hip_atomic_store((unsigned int*)(hw + rowg * 512 + cpair), pk,
                               __ATOMIC_RELAXED, __HIP_MEMORY_SCOPE_AGENT);
            *(unsigned int*)(Mp + rowg * 90112 + (long)(4 + ti) * 1024 + d * 512 + cpair) = pk;
        }

        // group barrier, prefetch inside the window:
        __syncthreads();            // drains h/Mp stores only (prefetch not yet issued)
        if (tid == 0)               // arrive
            __hip_atomic_fetch_add(cnt, 1u, __ATOMIC_RELAXED, __HIP_MEMORY_SCOPE_AGENT);
        if (t + 1 < T_SEQ) {        // pre prefetch for t+1: overlaps peers' arrival/spin
            const int tn = d ? (T_SEQ - 2 - t) : (t + 1);
            #pragma unroll
            for (int q = 0; q < 4; ++q) {
                const unsigned short* pb = pre + (long)d * 15728640 + ((long)(bb * 32 + rbase + q) * T_SEQ + tn) * 1536 + myc;
                pv[0][q] = bf2f(pb[0]); pv[1][q] = bf2f(pb[512]); pv[2][q] = bf2f(pb[1024]);
            }
        }
        if (tid == 0) {             // wait
            const unsigned int target = (unsigned int)(t + 1) * 16u;
            while (__hip_atomic_load(cnt, __ATOMIC_RELAXED, __HIP_MEMORY_SCOPE_AGENT) < target)
                __builtin_amdgcn_s_sleep(1);
        }
        __syncthreads();
    }
}

// Mask Mp in place (bf16 * {0,1} lossless) and mean over valid steps. mask is f32.
__global__ __launch_bounds__(256) void k_mask_mean(
    unsigned short* __restrict__ Mp, const float* __restrict__ mask,
    const int* __restrict__ lengths, float* __restrict__ mean)
{
    const int b = blockIdx.y;
    const int c = blockIdx.x * 256 + threadIdx.x;
    float acc = 0.f;
    unsigned short* base = Mp + (long)b * 90112 + 4096 + c;
    for (int t = 0; t < T_SEQ; ++t) {
        float m = mask[b * T_SEQ + t];
        float v = bf2f(base[t * 1024]) * m;
        base[t * 1024] = f2bf(v);
        acc += v;
    }
    mean[b * 1024 + c] = acc / (float)lengths[b];
}

// Conv epilogue over bf16 D: c[b,kf,t] = sum_i D[b, t-w+1+i, i*512+kf]; relu(bias+max_t).
__global__ __launch_bounds__(256) void k_conv_epi(
    const unsigned short* __restrict__ D, const float* __restrict__ cb,
    float* __restrict__ con, int w, int widx)
{
    const int b  = blockIdx.y;
    const int kf = blockIdx.x * 256 + threadIdx.x;
    const int N  = w * 512;
    const unsigned short* Db = D + (long)b * T_SEQ * N;
    float mx = -1e30f;
    for (int t = 0; t < T_SEQ + w - 1; ++t) {
        float s = 0.f;
        for (int i = 0; i < w; ++i) {
            int tau = t - w + 1 + i;
            if (tau >= 0 && tau < T_SEQ) s += bf2f(Db[(long)tau * N + i * 512 + kf]);
        }
        mx = fmaxf(mx, s);
    }
    con[b * 2048 + widx * 512 + kf] = fmaxf(0.f, mx + cb[kf]);
}

// Assemble map input (bf16 for MFMA map GEMM): [mean | con | videos_origin(f32)].
__global__ __launch_bounds__(256) void k_gather(
    const float* __restrict__ mean, const float* __restrict__ con,
    const float* __restrict__ vo, unsigned short* __restrict__ fin)
{
    int e = blockIdx.x * 256 + threadIdx.x;     // < 655360
    int b = e / 5120, k = e - b * 5120;
    float v;
    if (k < 1024)      v = mean[b * 1024 + k];
    else if (k < 3072) v = con[b * 2048 + (k - 1024)];
    else               v = vo[b * 2048 + (k - 3072)];
    fin[e] = f2bf(v);
}

// Reduce split-K partials + bias (f32) -> feat.
__global__ __launch_bounds__(256) void k_map_reduce(
    const float* __restrict__ part, const float* __restrict__ map_b,
    float* __restrict__ feat)
{
    int e = blockIdx.x * 256 + threadIdx.x;     // < 262144
    float s = map_b[e & 2047];
    #pragma unroll
    for (int z = 0; z < 8; ++z) s += part[(long)z * 262144 + e];
    feat[e] = s;
}

// BN (eval: /sqrt(1+eps)*gamma+beta) + row L2-normalize -> f32 out.
__global__ __launch_bounds__(256) void k_bn_norm(
    const float* __restrict__ feat, const float* __restrict__ gamma,
    const float* __restrict__ beta, float* __restrict__ out)
{
    const int b = blockIdx.x, tid = threadIdx.x;
    const float inv_c = 1.f / sqrtf(1.f + 1e-5f);
    float y[8]; float ss = 0.f;
    #pragma unroll
    for (int u = 0; u < 8; ++u) {
        int o = u * 256 + tid;
        float v = feat[b * 2048 + o] * inv_c * gamma[o] + beta[o];
        y[u] = v; ss += v * v;
    }
    #pragma unroll
    for (int off = 32; off >= 1; off >>= 1) ss += __shfl_down(ss, off, 64);
    __shared__ float rs[4];
    if ((tid & 63) == 0) rs[tid >> 6] = ss;
    __syncthreads();
    float rn = 1.f / sqrtf(rs[0] + rs[1] + rs[2] + rs[3]);
    #pragma unroll
    for (int u = 0; u < 8; ++u) {
        int o = u * 256 + tid;
        out[b * 2048 + o] = y[u] * rn;
    }
}

extern "C" void kernel_launch(void* const* d_in, const int* in_sizes, int n_in,
                              void* d_out, int out_size, void* d_ws, size_t ws_size,
                              hipStream_t stream)
{
    const float* videos  = (const float*)d_in[0];
    const float* vorigin = (const float*)d_in[1];
    const int*   lengths = (const int*)d_in[2];
    const float* mask    = (const float*)d_in[3];
    // d_in[4] gru_text_out: unused by the reference
    const float* Wih_f = (const float*)d_in[5];
    const float* Whh_f = (const float*)d_in[6];
    const float* bih_f = (const float*)d_in[7];
    const float* bhh_f = (const float*)d_in[8];
    const float* Wih_b = (const float*)d_in[9];
    const float* Whh_b = (const float*)d_in[10];
    const float* bih_b = (const float*)d_in[11];
    const float* bhh_b = (const float*)d_in[12];
    // d_in[13..16] attention: dead (softmax over size-1 axis == 1)
    const float* cw[4] = { (const float*)d_in[17], (const float*)d_in[19],
                           (const float*)d_in[21], (const float*)d_in[23] };
    const float* cb[4] = { (const float*)d_in[18], (const float*)d_in[20],
                           (const float*)d_in[22], (const float*)d_in[24] };
    const float* map_W = (const float*)d_in[25];
    const float* map_b = (const float*)d_in[26];
    const float* gamma = (const float*)d_in[27];
    const float* beta  = (const float*)d_in[28];

    // --- workspace layout (bytes) ---
    unsigned char* W = (unsigned char*)d_ws;
    unsigned short* pre    = (unsigned short*)W;               // [2][10240][1536] bf16 (GRU pre; conv D + part + mapw_bf alias later)
    unsigned short* Mp     = (unsigned short*)(W + 62914560);  // [128][88][1024] bf16
    unsigned short* hbf2   = (unsigned short*)(W + 85983232);  // [2 buf][2 dir][128][512] bf16
    unsigned int*   counters = (unsigned int*)(W + 86507520);  // [8][64] padded barrier counters (2048 B)
    float*          mean   = (float*)(W + 88342528);           // [128][1024] f32
    float*          con    = (float*)(W + 88866816);           // [128][2048] f32
    unsigned short* fin    = (unsigned short*)(W + 89915392);  // [128][5120] bf16
    float*          feat   = (float*)(W + 91226112);           // [128][2048] f32
    float*          part   = (float*)W;                        // [8][128][2048] f32, aliases pre (dead then)
    // time-multiplexed bf16 weight slots:
    unsigned short* wih_bf  = (unsigned short*)(W + 62914560); // 12.6MB in Mp region (dead pre-scan)
    unsigned short* cwbf    = (unsigned short*)(W + 57671680); // <=5.2MB pre-tail (conv D <= 52.4MB)
    unsigned short* mapw_bf = (unsigned short*)(W + 8388608);  // 21MB after part (pre dead post-conv)

    // zero hbf2 (t=0 reads buf0 = h(0)=0) and the padded barrier counters (every replay)
    hipMemsetAsync(W + 85983232, 0, 524288 + 2048, stream);

    // Wih (2 dirs, [1536][2048] f32 each) -> wih_bf bf16, contiguous [2][1536][2048]
    k_f2b<<<3072, 256, 0, stream>>>(Wih_f, wih_bf, 393216);
    k_f2b<<<3072, 256, 0, stream>>>(Wih_b, wih_bf + 3145728, 393216);

    // GRU input projection: pre[d][b*80+t][1536] = videos @ Wih_d^T + bih_d (bf16 out)
    // A = videos f32 (cvt_pk staged), B = wih_bf bf16 (gld16). Linear grid, by=id%80.
    gemm_mfma<1, 0, 1><<<dim3(24 * 80, 1, 1), 256, 0, stream>>>(
        videos, 0l, 10240, 0l, 2048,
        wih_bf, wih_bf + 3145728, 1536, 1536, 2048l, 0l,
        bih_f, bih_b, 1,
        pre, 15728640l, 1536l, 2048, 0l, 80);

    // Fused persistent GRU scan (round-7 protocol): one cooperative launch.
    {
        const unsigned short* prec = pre;
        void* args[] = { (void*)&prec, (void*)&hbf2, (void*)&Mp, (void*)&counters,
                         (void*)&Whh_f, (void*)&Whh_b, (void*)&bhh_f, (void*)&bhh_b };
        hipLaunchCooperativeKernel((const void*)k_gru_scan, dim3(128, 1, 1),
                                   dim3(256, 1, 1), args, 0, stream);
    }

    k_mask_mean<<<dim3(4, 128), 256, 0, stream>>>(Mp, mask, lengths, mean);

    // Convs: D[(b,tau),(i*512+kf)] = sum_d Mp[b,tau,d]*cw[kf,i,d] (bf16 D into pre region)
    // pure gld16 GEMMs; linear grid, by=id%80 for A (Mp) XCD locality.
    for (int wi = 0; wi < 4; ++wi) {
        int ww = wi + 2;
        int N  = ww * 512;
        k_f2b<<<ww * 256, 256, 0, stream>>>(cw[wi], cwbf, ww * 65536);
        gemm_mfma<0, 0, 1><<<dim3((N / 128) * 80, 1, 1), 256, 0, stream>>>(
            Mp, 4096l, 80, 90112l, 1024,
            cwbf, nullptr, 1 << 30, 512, (long)(ww * 1024), 1024l,
            nullptr, nullptr, 0,
            pre, 0l, (long)N, 1024, 0l, 80);
        k_conv_epi<<<dim3(2, 128), 256, 0, stream>>>(pre, cb[wi], con, ww, wi);
    }

    k_gather<<<2560, 256, 0, stream>>>(mean, con, vorigin, fin);

    // map: convert map_W -> bf16 (pre region beyond part is dead), split-K=8 GEMM.
    k_f2b<<<5120, 256, 0, stream>>>(map_W, mapw_bf, 1310720);
    gemm_mfma<0, 0, 0><<<dim3(16, 1, 8), 256, 0, stream>>>(
        fin, 0l, 128, 0l, 5120,
        mapw_bf, nullptr, 1 << 30, 2048, 5120l, 0l,
        nullptr, nullptr, 0,
        part, 0l, 2048l, 640, 262144l, 0);
    k_map_reduce<<<1024, 256, 0, stream>>>(part, map_b, feat);

    k_bn_norm<<<128, 256, 0, stream>>>(feat, gamma, beta, (float*)d_out);
}